// Round 1
// baseline (10763.386 us; speedup 1.0000x reference)
//
#include <hip/hip_runtime.h>
#include <math.h>

// ---------------- problem constants ----------------
#define EPSP 5.0f
#define BNEPS 1e-5f
constexpr int B_  = 64;    // batch
constexpr int T_  = 768;   // timesteps in
constexpr int D_  = 128;   // input feature
constexpr int E_  = 64;    // embedding (conv out channels)
constexpr int H_  = 128;   // hidden
constexpr int FH_ = 512;   // 4*H
constexpr int TC_ = 256;   // conv output steps
constexpr int O_  = 10;    // output classes

// ---------------- workspace layout (floats) ----------------
constexpr size_t EMB_OFF = 0;                                   // B*TC*E   [b][tc][e]
constexpr size_t SUM_OFF = EMB_OFF + (size_t)B_ * TC_ * E_;     // 128  (sum[64], ssq[64])
constexpr size_t SCL_OFF = SUM_OFF + 128;                       // 128  (scale[64], shift[64])
constexpr size_t WHH_OFF = SCL_OFF + 128;                       // 65536  packed [k4][j][4]
constexpr size_t WIH_OFF = WHH_OFF + (size_t)FH_ * H_;          // 32768  packed [e4][j][4]
constexpr size_t CWT_OFF = WIH_OFF + (size_t)FH_ * E_;          // 24576  [k][d][e]
constexpr size_t ZX_OFF  = CWT_OFF + (size_t)E_ * D_ * 3;       // B*TC*FH [b][t][j]
constexpr size_t WS_FLOATS = ZX_OFF + (size_t)B_ * TC_ * FH_;   // 9,560,320 floats (~38.2 MB)

__device__ inline float fast_rcp(float x) {
#if __has_builtin(__builtin_amdgcn_rcpf)
  return __builtin_amdgcn_rcpf(x);
#else
  return 1.0f / x;
#endif
}

// ---------------- prep: weight repack + zero BN sums ----------------
__global__ void prep_kernel(const float* __restrict__ conv_w,
                            const float* __restrict__ w_ih,
                            const float* __restrict__ w_hh,
                            float* __restrict__ ws) {
  int gid = blockIdx.x * blockDim.x + threadIdx.x;
  int nthr = gridDim.x * blockDim.x;
  for (int i = gid; i < 128; i += nthr) ws[SUM_OFF + i] = 0.f;
  // w_hh [512][128] -> packed [32][512][4] so z-GEMM loads are dwordx4-coalesced
  for (int s = gid; s < FH_ * H_; s += nthr) {
    int j = s >> 7, k = s & 127;
    ws[WHH_OFF + ((size_t)(k >> 2) * FH_ + j) * 4 + (k & 3)] = w_hh[s];
  }
  // w_ih [512][64] -> packed [16][512][4]
  for (int s = gid; s < FH_ * E_; s += nthr) {
    int j = s >> 6, e = s & 63;
    ws[WIH_OFF + ((size_t)(e >> 2) * FH_ + j) * 4 + (e & 3)] = w_ih[s];
  }
  // conv_w [e][d][k] -> [k][d][e] (lane-coalesced on e)
  for (int s = gid; s < E_ * D_ * 3; s += nthr) {
    int e = s / 384; int r = s - e * 384; int d = r / 3; int k = r - d * 3;
    ws[CWT_OFF + ((size_t)k * D_ + d) * E_ + e] = conv_w[s];
  }
}

// ---------------- conv + L2-normalize + BN partial sums ----------------
// grid: 64 b * 16 tc-groups = 1024 blocks, 256 threads. Each block: 16 tc (48 t rows).
__global__ __launch_bounds__(256) void conv_bn_kernel(const float* __restrict__ inputs,
                                                      const float* __restrict__ conv_b,
                                                      float* __restrict__ ws) {
  __shared__ float xin[48 * 129];   // stride 129 breaks bank aliasing
  __shared__ float rnorm[48];
  __shared__ float cwc[3 * 16 * 64];
  __shared__ float bnr1[256], bnr2[256];
  int tid = threadIdx.x;
  int bb = blockIdx.x >> 4, tcg = blockIdx.x & 15;
  const float* inp = inputs + ((size_t)bb * T_ + (size_t)tcg * 48) * D_;
  for (int idx = tid; idx < 48 * 128; idx += 256) {
    int r = idx >> 7, d = idx & 127;
    xin[r * 129 + d] = inp[idx];
  }
  __syncthreads();
  if (tid < 48) {
    float ss = 0.f;
    for (int d = 0; d < 128; ++d) { float v = xin[tid * 129 + d]; ss += v * v; }
    rnorm[tid] = 1.0f / fmaxf(sqrtf(ss), 1e-12f);
  }
  __syncthreads();
  for (int idx = tid; idx < 48 * 128; idx += 256) {
    int r = idx >> 7, d = idx & 127;
    xin[r * 129 + d] *= rnorm[r];
  }
  int e = tid & 63, tg = tid >> 6;
  float cb = conv_b[e];
  float acc[4];
#pragma unroll
  for (int q = 0; q < 4; ++q) acc[q] = cb;
  for (int ch = 0; ch < 8; ++ch) {
    __syncthreads();   // protect cwc reuse
    for (int idx = tid; idx < 3072; idx += 256) {
      int k = idx >> 10; int i2 = idx & 1023; int dd = i2 >> 6; int e2 = i2 & 63;
      cwc[idx] = ws[CWT_OFF + ((size_t)k * D_ + ch * 16 + dd) * E_ + e2];
    }
    __syncthreads();
    for (int dd = 0; dd < 16; ++dd) {
      int dcol = ch * 16 + dd;
#pragma unroll
      for (int k = 0; k < 3; ++k) {
        float w = cwc[(k * 16 + dd) * 64 + e];
#pragma unroll
        for (int q = 0; q < 4; ++q) {
          int tcl = tg * 4 + q;
          acc[q] += w * xin[(3 * tcl + k) * 129 + dcol];
        }
      }
    }
  }
  float ps = 0.f, pss = 0.f;
#pragma unroll
  for (int q = 0; q < 4; ++q) {
    int tcl = tg * 4 + q;
    ws[EMB_OFF + ((size_t)bb * TC_ + tcg * 16 + tcl) * E_ + e] = acc[q];
    ps += acc[q]; pss += acc[q] * acc[q];
  }
  bnr1[tg * 64 + e] = ps;
  bnr2[tg * 64 + e] = pss;
  __syncthreads();
  if (tid < 64) {
    float s1 = bnr1[tid] + bnr1[64 + tid] + bnr1[128 + tid] + bnr1[192 + tid];
    float s2 = bnr2[tid] + bnr2[64 + tid] + bnr2[128 + tid] + bnr2[192 + tid];
    atomicAdd(&ws[SUM_OFF + tid], s1);
    atomicAdd(&ws[SUM_OFF + 64 + tid], s2);
  }
}

// ---------------- BN finalize ----------------
__global__ void bn_finalize_kernel(const float* __restrict__ gamma,
                                   const float* __restrict__ beta,
                                   float* __restrict__ ws) {
  int e = threadIdx.x;
  if (e < 64) {
    const float n = (float)(B_ * TC_);
    float mean = ws[SUM_OFF + e] / n;
    float var = ws[SUM_OFF + 64 + e] / n - mean * mean;
    float sc = gamma[e] * rsqrtf(var + BNEPS);
    ws[SCL_OFF + e] = sc;
    ws[SCL_OFF + 64 + e] = beta[e] - mean * sc;
  }
}

// ---------------- z_x = relu(bn(emb)) @ w_ih^T + b_ih + b_hh ----------------
// grid: 64 b * 16 t-groups = 1024 blocks, 256 threads.
__global__ __launch_bounds__(256) void zx_kernel(const float* __restrict__ b_ih,
                                                 const float* __restrict__ b_hh,
                                                 float* __restrict__ ws) {
  __shared__ __align__(16) float actT[16 * 64];
  int tid = threadIdx.x;
  int bb = blockIdx.x >> 4, tg2 = blockIdx.x & 15;
  for (int idx = tid; idx < 1024; idx += 256) {
    int tl = idx >> 6, e2 = idx & 63;
    float v = ws[EMB_OFF + ((size_t)bb * TC_ + tg2 * 16 + tl) * E_ + e2];
    actT[idx] = fmaxf(v * ws[SCL_OFF + e2] + ws[SCL_OFF + 64 + e2], 0.f);
  }
  __syncthreads();
  int j0 = tid, j1 = tid + 256;
  float acc0[16], acc1[16];
  float bias0 = b_ih[j0] + b_hh[j0];
  float bias1 = b_ih[j1] + b_hh[j1];
#pragma unroll
  for (int tl = 0; tl < 16; ++tl) { acc0[tl] = bias0; acc1[tl] = bias1; }
  const float* wp = ws + WIH_OFF;
  for (int e4 = 0; e4 < 16; ++e4) {
    float4 w0 = *(const float4*)(wp + ((size_t)e4 * FH_ + j0) * 4);
    float4 w1 = *(const float4*)(wp + ((size_t)e4 * FH_ + j1) * 4);
#pragma unroll
    for (int tl = 0; tl < 16; ++tl) {
      float4 a4 = *(const float4*)(actT + tl * 64 + e4 * 4);
      acc0[tl] += w0.x * a4.x + w0.y * a4.y + w0.z * a4.z + w0.w * a4.w;
      acc1[tl] += w1.x * a4.x + w1.y * a4.y + w1.z * a4.z + w1.w * a4.w;
    }
  }
#pragma unroll
  for (int tl = 0; tl < 16; ++tl) {
    size_t base = ZX_OFF + ((size_t)bb * TC_ + tg2 * 16 + tl) * FH_;
    ws[base + j0] = acc0[tl];
    ws[base + j1] = acc1[tl];
  }
}

// ---------------- the sequential ProxLSTM scan: 1 block per batch ----------------
__global__ __launch_bounds__(512) void scan_kernel(const float* __restrict__ lin_w,
                                                   const float* __restrict__ lin_b,
                                                   const float* __restrict__ ws,
                                                   float* __restrict__ out) {
  __shared__ __align__(16) float h_s[128];
  __shared__ __align__(16) float c_s[128];
  __shared__ float z_s[512];
  __shared__ float s_s[128], a1_s[128], a2_s[128], a3_s[128], o_s[128];
  __shared__ __align__(16) float G_s[128 * 64];     // [h][e]
  __shared__ float M_s[64 * 65];                    // padded stride 65
  __shared__ __align__(16) float Lp_s[64 * 8];      // current chol panel, row-major (aligned b128 reads)
  __shared__ __align__(16) float y_s[64];
  __shared__ __align__(16) float red_s[512];

  int tid = threadIdx.x;
  int bb = blockIdx.x;
  int lane = tid & 63;
  if (tid < 128) { h_s[tid] = 0.f; c_s[tid] = 0.f; }
  __syncthreads();
  const float* whp = ws + WHH_OFF;
  const float* wip = ws + WIH_OFF;

  for (int t = 0; t < TC_; ++t) {
    // ---- P1: z = z_x + w_hh @ h  (thread j owns z[j]) ----
    {
      float acc = ws[ZX_OFF + ((size_t)bb * TC_ + t) * FH_ + tid];
#pragma unroll 4
      for (int k4 = 0; k4 < 32; ++k4) {
        float4 w = *(const float4*)(whp + ((size_t)k4 * FH_ + tid) * 4);
        float4 hv = *(const float4*)(h_s + k4 * 4);
        acc += w.x * hv.x + w.y * hv.y + w.z * hv.z + w.w * hv.w;
      }
      z_s[tid] = acc;
    }
    __syncthreads();
    // ---- P2: gates (torch order i,f,g,o) ----
    if (tid < 128) {
      float zi = z_s[tid], zf = z_s[128 + tid], zg = z_s[256 + tid], zo = z_s[384 + tid];
      float c = c_s[tid];
      float ig = 1.f / (1.f + expf(-zi));
      float fg = 1.f / (1.f + expf(-zf));
      float gg = tanhf(zg);
      float og = 1.f / (1.f + expf(-zo));
      s_s[tid] = fg * c + ig * gg;
      a1_s[tid] = ig * (1.f - ig) * gg;
      a2_s[tid] = fg * (1.f - fg) * c;
      a3_s[tid] = ig * (1.f - gg * gg);
      o_s[tid] = og;
    }
    __syncthreads();
    // ---- P3: G[h][e] = a1*Wi + a2*Wf + a3*Wg ----
    {
      int hh = tid >> 2, eq = (tid & 3) * 16;
      float a1 = a1_s[hh], a2 = a2_s[hh], a3 = a3_s[hh];
#pragma unroll
      for (int e4 = 0; e4 < 4; ++e4) {
        int ecol = eq + e4 * 4;
        int egrp = ecol >> 2;
        float4 wi = *(const float4*)(wip + ((size_t)egrp * FH_ + hh) * 4);
        float4 wf = *(const float4*)(wip + ((size_t)egrp * FH_ + 128 + hh) * 4);
        float4 wg = *(const float4*)(wip + ((size_t)egrp * FH_ + 256 + hh) * 4);
        float4 g;
        g.x = a1 * wi.x + a2 * wf.x + a3 * wg.x;
        g.y = a1 * wi.y + a2 * wf.y + a3 * wg.y;
        g.z = a1 * wi.z + a2 * wf.z + a3 * wg.z;
        g.w = a1 * wi.w + a2 * wf.w + a3 * wg.w;
        *(float4*)(G_s + hh * 64 + ecol) = g;
      }
    }
    __syncthreads();
    // ---- P4: M = I + eps*G^T G (wave w owns 8 output cols); P5a: y=G^T s partials ----
    {
      int w = tid >> 6;
      int e2b = w * 8;
      float acc8[8];
#pragma unroll
      for (int c = 0; c < 8; ++c) acc8[c] = 0.f;
#pragma unroll 4
      for (int hh = 0; hh < 128; ++hh) {
        float own = G_s[hh * 64 + lane];
        float4 b0 = *(const float4*)(G_s + hh * 64 + e2b);
        float4 b1 = *(const float4*)(G_s + hh * 64 + e2b + 4);
        acc8[0] += own * b0.x; acc8[1] += own * b0.y;
        acc8[2] += own * b0.z; acc8[3] += own * b0.w;
        acc8[4] += own * b1.x; acc8[5] += own * b1.y;
        acc8[6] += own * b1.z; acc8[7] += own * b1.w;
      }
#pragma unroll
      for (int c = 0; c < 8; ++c) {
        int e2 = e2b + c;
        M_s[lane * 65 + e2] = EPSP * acc8[c] + ((lane == e2) ? 1.f : 0.f);
      }
      float yp = 0.f;
#pragma unroll
      for (int ii = 0; ii < 16; ++ii) {
        int hh = w * 16 + ii;
        yp += G_s[hh * 64 + lane] * s_s[hh];
      }
      red_s[w * 64 + lane] = yp;
    }
    __syncthreads();
    if (tid < 64) {
      float y = 0.f;
#pragma unroll
      for (int g2 = 0; g2 < 8; ++g2) y += red_s[g2 * 64 + tid];
      y_s[tid] = y;
    }
    __syncthreads();
    // ---- P6: wave-0 Cholesky (panel-8, shfl pivots) + triangular solves ----
    if (tid < 64) {
      for (int pan = 0; pan < 8; ++pan) {
        int j0 = pan * 8;
        float p[8];
#pragma unroll
        for (int jj = 0; jj < 8; ++jj) p[jj] = M_s[lane * 65 + j0 + jj];
#pragma unroll
        for (int jj = 0; jj < 8; ++jj) {
          float d = __shfl(p[jj], j0 + jj);
          float l = sqrtf(d);
          float inv = fast_rcp(l);
          float scaled = p[jj] * inv;
          p[jj] = (lane == (j0 + jj)) ? l : scaled;
#pragma unroll
          for (int kk = jj + 1; kk < 8; ++kk) {
            float Lkj = __shfl(p[jj], j0 + kk);
            p[kk] -= p[jj] * Lkj;
          }
        }
#pragma unroll
        for (int jj = 0; jj < 8; ++jj) {
          Lp_s[lane * 8 + jj] = p[jj];
          M_s[lane * 65 + j0 + jj] = p[jj];
        }
        for (int k = j0 + 8; k < 64; ++k) {
          float4 b0 = *(const float4*)(Lp_s + k * 8);
          float4 b1 = *(const float4*)(Lp_s + k * 8 + 4);
          float own = M_s[lane * 65 + k];
          own -= p[0] * b0.x + p[1] * b0.y + p[2] * b0.z + p[3] * b0.w
               + p[4] * b1.x + p[5] * b1.y + p[6] * b1.z + p[7] * b1.w;
          M_s[lane * 65 + k] = own;
        }
      }
      float dinv = fast_rcp(M_s[lane * 65 + lane]);
      float yl = y_s[lane];
      // forward: L y' = y
      for (int i2 = 0; i2 < 64; ++i2) {
        float v = __shfl(yl, i2) * __shfl(dinv, i2);
        float Lki = M_s[lane * 65 + i2];
        float upd = yl - Lki * v;
        yl = (lane == i2) ? v : ((lane > i2) ? upd : yl);
      }
      // backward: L^T x = y'
      for (int i2 = 63; i2 >= 0; --i2) {
        float v = __shfl(yl, i2) * __shfl(dinv, i2);
        float Lik = M_s[i2 * 65 + lane];
        float upd = yl - Lik * v;
        yl = (lane == i2) ? v : ((lane < i2) ? upd : yl);
      }
      y_s[lane] = yl;   // x
    }
    __syncthreads();
    // ---- P7: u = G x ; c = s - eps*u ; h = o*tanh(c) ----
    {
      int hh = tid >> 2, part = tid & 3;
      float up = 0.f;
#pragma unroll
      for (int q = 0; q < 4; ++q) {
        int ecol = part * 16 + q * 4;
        float4 gv = *(const float4*)(G_s + hh * 64 + ecol);
        float4 xv = *(const float4*)(y_s + ecol);
        up += gv.x * xv.x + gv.y * xv.y + gv.z * xv.z + gv.w * xv.w;
      }
      red_s[tid] = up;   // tid == hh*4+part
    }
    __syncthreads();
    if (tid < 128) {
      float4 r4 = *(const float4*)(red_s + tid * 4);
      float u = r4.x + r4.y + r4.z + r4.w;
      float cn = s_s[tid] - EPSP * u;
      float hn = o_s[tid] * tanhf(cn);
      c_s[tid] = cn;
      h_s[tid] = hn;
    }
    __syncthreads();
  }
  // ---- head: out = h_last @ lin_w^T + lin_b ----
  if (tid < O_) {
    float acc = lin_b[tid];
    for (int hh2 = 0; hh2 < 128; ++hh2) acc += h_s[hh2] * lin_w[tid * 128 + hh2];
    out[(size_t)bb * O_ + tid] = acc;
  }
}

// ---------------- launch ----------------
extern "C" void kernel_launch(void* const* d_in, const int* in_sizes, int n_in,
                              void* d_out, int out_size, void* d_ws, size_t ws_size,
                              hipStream_t stream) {
  (void)in_sizes; (void)n_in; (void)out_size;
  const float* inputs  = (const float*)d_in[0];
  // d_in[1] = r (unused in ProxLSTM mode)
  const float* conv_w  = (const float*)d_in[2];
  const float* conv_b  = (const float*)d_in[3];
  const float* gamma   = (const float*)d_in[4];
  const float* beta    = (const float*)d_in[5];
  const float* w_ih    = (const float*)d_in[6];
  const float* w_hh    = (const float*)d_in[7];
  const float* b_ih    = (const float*)d_in[8];
  const float* b_hh    = (const float*)d_in[9];
  const float* lin_w   = (const float*)d_in[10];
  const float* lin_b   = (const float*)d_in[11];
  float* out = (float*)d_out;
  float* ws  = (float*)d_ws;

  if (ws_size < WS_FLOATS * sizeof(float)) return;  // insufficient scratch -> fail cleanly

  hipLaunchKernelGGL(prep_kernel, dim3(192), dim3(256), 0, stream, conv_w, w_ih, w_hh, ws);
  hipLaunchKernelGGL(conv_bn_kernel, dim3(1024), dim3(256), 0, stream, inputs, conv_b, ws);
  hipLaunchKernelGGL(bn_finalize_kernel, dim3(1), dim3(64), 0, stream, gamma, beta, ws);
  hipLaunchKernelGGL(zx_kernel, dim3(1024), dim3(256), 0, stream, b_ih, b_hh, ws);
  hipLaunchKernelGGL(scan_kernel, dim3(64), dim3(512), 0, stream, lin_w, lin_b, ws, out);
}

// Round 2
// 7868.842 us; speedup vs baseline: 1.3678x; 1.3678x over previous
//
#include <hip/hip_runtime.h>
#include <math.h>

// ---------------- problem constants ----------------
#define EPSP 5.0f
#define BNEPS 1e-5f
constexpr int B_  = 64;    // batch
constexpr int T_  = 768;   // timesteps in
constexpr int D_  = 128;   // input feature
constexpr int E_  = 64;    // embedding (conv out channels)
constexpr int H_  = 128;   // hidden
constexpr int FH_ = 512;   // 4*H
constexpr int TC_ = 256;   // conv output steps
constexpr int O_  = 10;    // output classes

// ---------------- workspace layout (floats) ----------------
constexpr size_t EMB_OFF = 0;                                   // B*TC*E   [b][tc][e]
constexpr size_t SUM_OFF = EMB_OFF + (size_t)B_ * TC_ * E_;     // 128  (sum[64], ssq[64])
constexpr size_t SCL_OFF = SUM_OFF + 128;                       // 128  (scale[64], shift[64])
constexpr size_t WHH_OFF = SCL_OFF + 128;                       // 65536  (unused this rev)
constexpr size_t WIH_OFF = WHH_OFF + (size_t)FH_ * H_;          // 32768  packed [e4][j][4]
constexpr size_t CWT_OFF = WIH_OFF + (size_t)FH_ * E_;          // 24576  [k][d][e]
constexpr size_t ZX_OFF  = CWT_OFF + (size_t)E_ * D_ * 3;       // B*TC*FH [b][t][j]
constexpr size_t WS_FLOATS = ZX_OFF + (size_t)B_ * TC_ * FH_;

__device__ inline float fast_rcp(float x) {
#if __has_builtin(__builtin_amdgcn_rcpf)
  return __builtin_amdgcn_rcpf(x);
#else
  return 1.0f / x;
#endif
}
__device__ inline float frsq(float x) {
#if __has_builtin(__builtin_amdgcn_rsqf)
  return __builtin_amdgcn_rsqf(x);
#else
  return rsqrtf(x);
#endif
}
__device__ inline float fexp2(float x) {
#if __has_builtin(__builtin_amdgcn_exp2f)
  return __builtin_amdgcn_exp2f(x);
#else
  return exp2f(x);
#endif
}
// readlane broadcast: uniform-lane VGPR -> SGPR, ~6 cyc (vs ~100+ for ds_bpermute shfl)
__device__ inline float rl(float v, int lane) {
  return __int_as_float(__builtin_amdgcn_readlane(__float_as_int(v), lane));
}
#define LOG2E 1.4426950408889634f
__device__ inline float fsigmoid(float x) {
  return fast_rcp(1.f + fexp2(-LOG2E * x));
}
__device__ inline float ftanh(float x) {
  return 1.f - 2.f * fast_rcp(1.f + fexp2(2.f * LOG2E * x));
}

// ---------------- prep: weight repack + zero BN sums ----------------
__global__ void prep_kernel(const float* __restrict__ conv_w,
                            const float* __restrict__ w_ih,
                            float* __restrict__ ws) {
  int gid = blockIdx.x * blockDim.x + threadIdx.x;
  int nthr = gridDim.x * blockDim.x;
  for (int i = gid; i < 128; i += nthr) ws[SUM_OFF + i] = 0.f;
  // w_ih [512][64] -> packed [16][512][4]
  for (int s = gid; s < FH_ * E_; s += nthr) {
    int j = s >> 6, e = s & 63;
    ws[WIH_OFF + ((size_t)(e >> 2) * FH_ + j) * 4 + (e & 3)] = w_ih[s];
  }
  // conv_w [e][d][k] -> [k][d][e]
  for (int s = gid; s < E_ * D_ * 3; s += nthr) {
    int e = s / 384; int r = s - e * 384; int d = r / 3; int k = r - d * 3;
    ws[CWT_OFF + ((size_t)k * D_ + d) * E_ + e] = conv_w[s];
  }
}

// ---------------- conv + L2-normalize + BN partial sums ----------------
__global__ __launch_bounds__(256) void conv_bn_kernel(const float* __restrict__ inputs,
                                                      const float* __restrict__ conv_b,
                                                      float* __restrict__ ws) {
  __shared__ float xin[48 * 129];
  __shared__ float rnorm[48];
  __shared__ float cwc[3 * 16 * 64];
  __shared__ float bnr1[256], bnr2[256];
  int tid = threadIdx.x;
  int bb = blockIdx.x >> 4, tcg = blockIdx.x & 15;
  const float* inp = inputs + ((size_t)bb * T_ + (size_t)tcg * 48) * D_;
  for (int idx = tid; idx < 48 * 128; idx += 256) {
    int r = idx >> 7, d = idx & 127;
    xin[r * 129 + d] = inp[idx];
  }
  __syncthreads();
  if (tid < 48) {
    float ss = 0.f;
    for (int d = 0; d < 128; ++d) { float v = xin[tid * 129 + d]; ss += v * v; }
    rnorm[tid] = 1.0f / fmaxf(sqrtf(ss), 1e-12f);
  }
  __syncthreads();
  for (int idx = tid; idx < 48 * 128; idx += 256) {
    int r = idx >> 7, d = idx & 127;
    xin[r * 129 + d] *= rnorm[r];
  }
  int e = tid & 63, tg = tid >> 6;
  float cb = conv_b[e];
  float acc[4];
#pragma unroll
  for (int q = 0; q < 4; ++q) acc[q] = cb;
  for (int ch = 0; ch < 8; ++ch) {
    __syncthreads();
    for (int idx = tid; idx < 3072; idx += 256) {
      int k = idx >> 10; int i2 = idx & 1023; int dd = i2 >> 6; int e2 = i2 & 63;
      cwc[idx] = ws[CWT_OFF + ((size_t)k * D_ + ch * 16 + dd) * E_ + e2];
    }
    __syncthreads();
    for (int dd = 0; dd < 16; ++dd) {
      int dcol = ch * 16 + dd;
#pragma unroll
      for (int k = 0; k < 3; ++k) {
        float w = cwc[(k * 16 + dd) * 64 + e];
#pragma unroll
        for (int q = 0; q < 4; ++q) {
          int tcl = tg * 4 + q;
          acc[q] += w * xin[(3 * tcl + k) * 129 + dcol];
        }
      }
    }
  }
  float ps = 0.f, pss = 0.f;
#pragma unroll
  for (int q = 0; q < 4; ++q) {
    int tcl = tg * 4 + q;
    ws[EMB_OFF + ((size_t)bb * TC_ + tcg * 16 + tcl) * E_ + e] = acc[q];
    ps += acc[q]; pss += acc[q] * acc[q];
  }
  bnr1[tg * 64 + e] = ps;
  bnr2[tg * 64 + e] = pss;
  __syncthreads();
  if (tid < 64) {
    float s1 = bnr1[tid] + bnr1[64 + tid] + bnr1[128 + tid] + bnr1[192 + tid];
    float s2 = bnr2[tid] + bnr2[64 + tid] + bnr2[128 + tid] + bnr2[192 + tid];
    atomicAdd(&ws[SUM_OFF + tid], s1);
    atomicAdd(&ws[SUM_OFF + 64 + tid], s2);
  }
}

// ---------------- BN finalize ----------------
__global__ void bn_finalize_kernel(const float* __restrict__ gamma,
                                   const float* __restrict__ beta,
                                   float* __restrict__ ws) {
  int e = threadIdx.x;
  if (e < 64) {
    const float n = (float)(B_ * TC_);
    float mean = ws[SUM_OFF + e] / n;
    float var = ws[SUM_OFF + 64 + e] / n - mean * mean;
    float sc = gamma[e] * rsqrtf(var + BNEPS);
    ws[SCL_OFF + e] = sc;
    ws[SCL_OFF + 64 + e] = beta[e] - mean * sc;
  }
}

// ---------------- z_x = relu(bn(emb)) @ w_ih^T + b_ih + b_hh ----------------
__global__ __launch_bounds__(256) void zx_kernel(const float* __restrict__ b_ih,
                                                 const float* __restrict__ b_hh,
                                                 float* __restrict__ ws) {
  __shared__ __align__(16) float actT[16 * 64];
  int tid = threadIdx.x;
  int bb = blockIdx.x >> 4, tg2 = blockIdx.x & 15;
  for (int idx = tid; idx < 1024; idx += 256) {
    int tl = idx >> 6, e2 = idx & 63;
    float v = ws[EMB_OFF + ((size_t)bb * TC_ + tg2 * 16 + tl) * E_ + e2];
    actT[idx] = fmaxf(v * ws[SCL_OFF + e2] + ws[SCL_OFF + 64 + e2], 0.f);
  }
  __syncthreads();
  int j0 = tid, j1 = tid + 256;
  float acc0[16], acc1[16];
  float bias0 = b_ih[j0] + b_hh[j0];
  float bias1 = b_ih[j1] + b_hh[j1];
#pragma unroll
  for (int tl = 0; tl < 16; ++tl) { acc0[tl] = bias0; acc1[tl] = bias1; }
  const float* wp = ws + WIH_OFF;
  for (int e4 = 0; e4 < 16; ++e4) {
    float4 w0 = *(const float4*)(wp + ((size_t)e4 * FH_ + j0) * 4);
    float4 w1 = *(const float4*)(wp + ((size_t)e4 * FH_ + j1) * 4);
#pragma unroll
    for (int tl = 0; tl < 16; ++tl) {
      float4 a4 = *(const float4*)(actT + tl * 64 + e4 * 4);
      acc0[tl] += w0.x * a4.x + w0.y * a4.y + w0.z * a4.z + w0.w * a4.w;
      acc1[tl] += w1.x * a4.x + w1.y * a4.y + w1.z * a4.z + w1.w * a4.w;
    }
  }
#pragma unroll
  for (int tl = 0; tl < 16; ++tl) {
    size_t base = ZX_OFF + ((size_t)bb * TC_ + tg2 * 16 + tl) * FH_;
    ws[base + j0] = acc0[tl];
    ws[base + j1] = acc1[tl];
  }
}

// ---------------- the sequential ProxLSTM scan: 1 block per batch ----------------
// G_s row stride 68 breaks power-of-2 bank aliasing for row reads.
#define GS 68
__global__ __launch_bounds__(512, 2) void scan_kernel(const float* __restrict__ w_hh,
                                                      const float* __restrict__ lin_w,
                                                      const float* __restrict__ lin_b,
                                                      const float* __restrict__ ws,
                                                      float* __restrict__ out) {
  __shared__ __align__(16) float h_s[128];
  __shared__ __align__(16) float c_s[128];
  __shared__ float z_s[512];
  __shared__ float s_s[128], o_s[128];
  __shared__ __align__(16) float G_s[128 * GS];
  __shared__ float M_s[64 * 65];
  __shared__ float Lp_s[16 * 64];     // current panel, transposed [jj][row]
  __shared__ __align__(16) float y_s[64];
  __shared__ __align__(16) float red_s[512];

  int tid = threadIdx.x;
  int bb = blockIdx.x;
  int lane = tid & 63;
  int wv = tid >> 6;

  // hold this thread's w_hh row (z[tid] row) in 128 VGPRs
  float4 w4[32];
  {
    const float4* wr = (const float4*)(w_hh + (size_t)tid * H_);
#pragma unroll
    for (int k = 0; k < 32; ++k) w4[k] = wr[k];
  }
  if (tid < 128) { h_s[tid] = 0.f; c_s[tid] = 0.f; }
  __syncthreads();

  const float4* wip4 = (const float4*)(ws + WIH_OFF);
  float dinv = 1.f;   // per-lane 1/L[lane][lane] (wave 0 only)
  float zx_next = ws[ZX_OFF + ((size_t)bb * TC_) * FH_ + tid];

  for (int t = 0; t < TC_; ++t) {
    // ---- A: z = z_x + w_hh @ h ----
    {
      float acc = zx_next;
      if (t + 1 < TC_) zx_next = ws[ZX_OFF + ((size_t)bb * TC_ + t + 1) * FH_ + tid];
      const float4* h4 = (const float4*)h_s;
#pragma unroll 8
      for (int k = 0; k < 32; ++k) {
        float4 hv = h4[k];
        acc += w4[k].x * hv.x + w4[k].y * hv.y + w4[k].z * hv.z + w4[k].w * hv.w;
      }
      z_s[tid] = acc;
    }
    __syncthreads();
    // ---- B: gates (redundant per quad) + G row-quarter ----
    {
      int hh = tid >> 2, q = tid & 3;
      float zi = z_s[hh], zf = z_s[128 + hh], zg = z_s[256 + hh], zo = z_s[384 + hh];
      float c = c_s[hh];
      float ig = fsigmoid(zi);
      float fg = fsigmoid(zf);
      float gg = ftanh(zg);
      float a1 = ig * (1.f - ig) * gg;
      float a2 = fg * (1.f - fg) * c;
      float a3 = ig * (1.f - gg * gg);
      if (q == 0) {
        s_s[hh] = fg * c + ig * gg;
        o_s[hh] = fsigmoid(zo);
      }
#pragma unroll
      for (int e4 = 0; e4 < 4; ++e4) {
        int eg = q * 4 + e4;
        float4 wi = wip4[(size_t)eg * FH_ + hh];
        float4 wf = wip4[(size_t)eg * FH_ + 128 + hh];
        float4 wg = wip4[(size_t)eg * FH_ + 256 + hh];
        float4 g;
        g.x = a1 * wi.x + a2 * wf.x + a3 * wg.x;
        g.y = a1 * wi.y + a2 * wf.y + a3 * wg.y;
        g.z = a1 * wi.z + a2 * wf.z + a3 * wg.z;
        g.w = a1 * wi.w + a2 * wf.w + a3 * wg.w;
        *(float4*)(G_s + hh * GS + eg * 4) = g;
      }
    }
    __syncthreads();
    // ---- C: M = I + eps*G^T G (wave wv owns 8 cols) + y partials ----
    {
      int e2b = wv * 8;
      float acc8[8];
#pragma unroll
      for (int c = 0; c < 8; ++c) acc8[c] = 0.f;
#pragma unroll 4
      for (int hh = 0; hh < 128; ++hh) {
        float own = G_s[hh * GS + lane];
        float4 b0 = *(const float4*)(G_s + hh * GS + e2b);
        float4 b1 = *(const float4*)(G_s + hh * GS + e2b + 4);
        acc8[0] += own * b0.x; acc8[1] += own * b0.y;
        acc8[2] += own * b0.z; acc8[3] += own * b0.w;
        acc8[4] += own * b1.x; acc8[5] += own * b1.y;
        acc8[6] += own * b1.z; acc8[7] += own * b1.w;
      }
#pragma unroll
      for (int c = 0; c < 8; ++c) {
        int e2 = e2b + c;
        M_s[lane * 65 + e2] = EPSP * acc8[c] + ((lane == e2) ? 1.f : 0.f);
      }
      float yp = 0.f;
#pragma unroll
      for (int ii = 0; ii < 16; ++ii) {
        int hh = wv * 16 + ii;
        yp += G_s[hh * GS + lane] * s_s[hh];
      }
      red_s[wv * 64 + lane] = yp;
    }
    __syncthreads();
    // ---- D: Cholesky, panel-16, readlane pivots; multi-wave trailing ----
#pragma unroll 1
    for (int pan = 0; pan < 4; ++pan) {
      int j0 = pan * 16;
      if (tid < 64) {
        float p[16];
#pragma unroll
        for (int jj = 0; jj < 16; ++jj) p[jj] = M_s[lane * 65 + j0 + jj];
#pragma unroll
        for (int jj = 0; jj < 16; ++jj) {
          float d  = rl(p[jj], j0 + jj);
          float rs = frsq(d);
          p[jj] *= rs;                         // diag lane: d*rs = sqrt(d)
          dinv = (lane == j0 + jj) ? rs : dinv;
#pragma unroll
          for (int kk = jj + 1; kk < 16; ++kk) {
            float l = rl(p[jj], j0 + kk);      // L[j0+kk][jj], SGPR
            p[kk] -= p[jj] * l;                // v_fma with SGPR operand
          }
        }
#pragma unroll
        for (int jj = 0; jj < 16; ++jj) {
          M_s[lane * 65 + j0 + jj] = p[jj];
          Lp_s[jj * 64 + lane] = p[jj];
        }
        if (pan == 3) {
          // y reduce + solves (still wave 0, no barrier needed)
          float r = 0.f;
#pragma unroll
          for (int g2 = 0; g2 < 8; ++g2) r += red_s[g2 * 64 + lane];
          // forward: L y' = y
          for (int i = 0; i < 64; ++i) {
            float Lri = M_s[lane * 65 + i];
            float sv  = rl(r, i);
            float sdv = rl(dinv, i);
            float vv  = sv * sdv;
            float upd = r - Lri * vv;
            r = (lane == i) ? vv : ((lane > i) ? upd : r);
          }
          // backward: L^T x = y'
          for (int i = 63; i >= 0; --i) {
            float Lil = M_s[i * 65 + lane];
            float sv  = rl(r, i);
            float sdv = rl(dinv, i);
            float vv  = sv * sdv;
            float upd = r - Lil * vv;
            r = (lane == i) ? vv : ((lane < i) ? upd : r);
          }
          y_s[lane] = r;
        }
      }
      __syncthreads();
      if (pan < 3) {
        float Lrow[16];
#pragma unroll
        for (int jj = 0; jj < 16; ++jj) Lrow[jj] = Lp_s[jj * 64 + lane];
        for (int k = j0 + 16 + wv; k < 64; k += 8) {
          float acc = M_s[lane * 65 + k];
#pragma unroll
          for (int jj = 0; jj < 16; ++jj) acc -= Lrow[jj] * Lp_s[jj * 64 + k];
          M_s[lane * 65 + k] = acc;
        }
        __syncthreads();
      }
    }
    // ---- E1: u = G x partials ----
    {
      int hh = tid >> 2, part = tid & 3;
      float up = 0.f;
#pragma unroll
      for (int q = 0; q < 4; ++q) {
        int ecol = part * 16 + q * 4;
        float4 gv = *(const float4*)(G_s + hh * GS + ecol);
        float4 xv = *(const float4*)(y_s + ecol);
        up += gv.x * xv.x + gv.y * xv.y + gv.z * xv.z + gv.w * xv.w;
      }
      red_s[tid] = up;
    }
    __syncthreads();
    // ---- E2: c,h update ----
    if (tid < 128) {
      float4 r4 = *(const float4*)(red_s + tid * 4);
      float u = r4.x + r4.y + r4.z + r4.w;
      float cn = s_s[tid] - EPSP * u;
      float hn = o_s[tid] * ftanh(cn);
      c_s[tid] = cn;
      h_s[tid] = hn;
    }
    __syncthreads();
  }
  // ---- head ----
  if (tid < O_) {
    float acc = lin_b[tid];
    for (int hh2 = 0; hh2 < 128; ++hh2) acc += h_s[hh2] * lin_w[tid * 128 + hh2];
    out[(size_t)bb * O_ + tid] = acc;
  }
}

// ---------------- launch ----------------
extern "C" void kernel_launch(void* const* d_in, const int* in_sizes, int n_in,
                              void* d_out, int out_size, void* d_ws, size_t ws_size,
                              hipStream_t stream) {
  (void)in_sizes; (void)n_in; (void)out_size;
  const float* inputs  = (const float*)d_in[0];
  const float* conv_w  = (const float*)d_in[2];
  const float* conv_b  = (const float*)d_in[3];
  const float* gamma   = (const float*)d_in[4];
  const float* beta    = (const float*)d_in[5];
  const float* w_ih    = (const float*)d_in[6];
  const float* w_hh    = (const float*)d_in[7];
  const float* b_ih    = (const float*)d_in[8];
  const float* b_hh    = (const float*)d_in[9];
  const float* lin_w   = (const float*)d_in[10];
  const float* lin_b   = (const float*)d_in[11];
  float* out = (float*)d_out;
  float* ws  = (float*)d_ws;

  if (ws_size < WS_FLOATS * sizeof(float)) return;

  hipLaunchKernelGGL(prep_kernel, dim3(192), dim3(256), 0, stream, conv_w, w_ih, ws);
  hipLaunchKernelGGL(conv_bn_kernel, dim3(1024), dim3(256), 0, stream, inputs, conv_b, ws);
  hipLaunchKernelGGL(bn_finalize_kernel, dim3(1), dim3(64), 0, stream, gamma, beta, ws);
  hipLaunchKernelGGL(zx_kernel, dim3(1024), dim3(256), 0, stream, b_ih, b_hh, ws);
  hipLaunchKernelGGL(scan_kernel, dim3(64), dim3(512), 0, stream, w_hh, lin_w, lin_b, ws, out);
}

// Round 3
// 6452.013 us; speedup vs baseline: 1.6682x; 1.2196x over previous
//
#include <hip/hip_runtime.h>
#include <math.h>

// ---------------- problem constants ----------------
#define EPSP 5.0f
#define BNEPS 1e-5f
constexpr int B_  = 64;    // batch
constexpr int T_  = 768;   // timesteps in
constexpr int D_  = 128;   // input feature
constexpr int E_  = 64;    // embedding (conv out channels)
constexpr int H_  = 128;   // hidden
constexpr int FH_ = 512;   // 4*H
constexpr int TC_ = 256;   // conv output steps
constexpr int O_  = 10;    // output classes

// ---------------- workspace layout (floats) ----------------
constexpr size_t EMB_OFF = 0;                                   // B*TC*E   [b][tc][e]
constexpr size_t SUM_OFF = EMB_OFF + (size_t)B_ * TC_ * E_;     // 128  (sum[64], ssq[64])
constexpr size_t SCL_OFF = SUM_OFF + 128;                       // 128  (scale[64], shift[64])
constexpr size_t WT_OFF  = SCL_OFF + 128;                       // 24576: w_ih transposed [gate(i,f,g)][e][j]
constexpr size_t WIH_OFF = WT_OFF + (size_t)FH_ * H_;           // 32768  packed [e4][j][4] (zx_kernel)
constexpr size_t CWT_OFF = WIH_OFF + (size_t)FH_ * E_;          // 24576  [k][d][e]
constexpr size_t ZX_OFF  = CWT_OFF + (size_t)E_ * D_ * 3;       // B*TC*FH [b][t][j]
constexpr size_t WS_FLOATS = ZX_OFF + (size_t)B_ * TC_ * FH_;

typedef __bf16 bf16x8 __attribute__((ext_vector_type(8)));
typedef __bf16 bf16x2 __attribute__((ext_vector_type(2)));
typedef float  floatx4 __attribute__((ext_vector_type(4)));

__device__ inline float fast_rcp(float x) {
#if __has_builtin(__builtin_amdgcn_rcpf)
  return __builtin_amdgcn_rcpf(x);
#else
  return 1.0f / x;
#endif
}
__device__ inline float frsq(float x) {
#if __has_builtin(__builtin_amdgcn_rsqf)
  return __builtin_amdgcn_rsqf(x);
#else
  return rsqrtf(x);
#endif
}
__device__ inline float fexp2(float x) {
#if __has_builtin(__builtin_amdgcn_exp2f)
  return __builtin_amdgcn_exp2f(x);
#else
  return exp2f(x);
#endif
}
__device__ inline float rl(float v, int lane) {
  return __int_as_float(__builtin_amdgcn_readlane(__float_as_int(v), lane));
}
#define LOG2E 1.4426950408889634f
__device__ inline float fsigmoid(float x) {
  return fast_rcp(1.f + fexp2(-LOG2E * x));
}
__device__ inline float ftanh(float x) {
  return 1.f - 2.f * fast_rcp(1.f + fexp2(2.f * LOG2E * x));
}

// ---------------- prep: weight repack + zero BN sums ----------------
__global__ void prep_kernel(const float* __restrict__ conv_w,
                            const float* __restrict__ w_ih,
                            float* __restrict__ ws) {
  int gid = blockIdx.x * blockDim.x + threadIdx.x;
  int nthr = gridDim.x * blockDim.x;
  for (int i = gid; i < 128; i += nthr) ws[SUM_OFF + i] = 0.f;
  // w_ih [512][64] -> packed [16][512][4]  (zx_kernel)
  for (int s = gid; s < FH_ * E_; s += nthr) {
    int j = s >> 6, e = s & 63;
    ws[WIH_OFF + ((size_t)(e >> 2) * FH_ + j) * 4 + (e & 3)] = w_ih[s];
  }
  // w_ih gates i,f,g transposed: Wt[g][e][j] = w_ih[(g*128+j)*64+e]  (scan G-build)
  for (int s = gid; s < 3 * H_ * E_ * 2; s += nthr) {   // 3*64*128 = 24576
    int g = s >> 13; int r = s & 8191; int e = r >> 7; int j = r & 127;
    ws[WT_OFF + s] = w_ih[((size_t)(g * 128 + j)) * 64 + e];
  }
  // conv_w [e][d][k] -> [k][d][e]
  for (int s = gid; s < E_ * D_ * 3; s += nthr) {
    int e = s / 384; int r = s - e * 384; int d = r / 3; int k = r - d * 3;
    ws[CWT_OFF + ((size_t)k * D_ + d) * E_ + e] = conv_w[s];
  }
}

// ---------------- conv + L2-normalize + BN partial sums ----------------
__global__ __launch_bounds__(256) void conv_bn_kernel(const float* __restrict__ inputs,
                                                      const float* __restrict__ conv_b,
                                                      float* __restrict__ ws) {
  __shared__ float xin[48 * 129];
  __shared__ float rnorm[48];
  __shared__ float cwc[3 * 16 * 64];
  __shared__ float bnr1[256], bnr2[256];
  int tid = threadIdx.x;
  int bb = blockIdx.x >> 4, tcg = blockIdx.x & 15;
  const float* inp = inputs + ((size_t)bb * T_ + (size_t)tcg * 48) * D_;
  for (int idx = tid; idx < 48 * 128; idx += 256) {
    int r = idx >> 7, d = idx & 127;
    xin[r * 129 + d] = inp[idx];
  }
  __syncthreads();
  if (tid < 48) {
    float ss = 0.f;
    for (int d = 0; d < 128; ++d) { float v = xin[tid * 129 + d]; ss += v * v; }
    rnorm[tid] = 1.0f / fmaxf(sqrtf(ss), 1e-12f);
  }
  __syncthreads();
  for (int idx = tid; idx < 48 * 128; idx += 256) {
    int r = idx >> 7, d = idx & 127;
    xin[r * 129 + d] *= rnorm[r];
  }
  int e = tid & 63, tg = tid >> 6;
  float cb = conv_b[e];
  float acc[4];
#pragma unroll
  for (int q = 0; q < 4; ++q) acc[q] = cb;
  for (int ch = 0; ch < 8; ++ch) {
    __syncthreads();
    for (int idx = tid; idx < 3072; idx += 256) {
      int k = idx >> 10; int i2 = idx & 1023; int dd = i2 >> 6; int e2 = i2 & 63;
      cwc[idx] = ws[CWT_OFF + ((size_t)k * D_ + ch * 16 + dd) * E_ + e2];
    }
    __syncthreads();
    for (int dd = 0; dd < 16; ++dd) {
      int dcol = ch * 16 + dd;
#pragma unroll
      for (int k = 0; k < 3; ++k) {
        float w = cwc[(k * 16 + dd) * 64 + e];
#pragma unroll
        for (int q = 0; q < 4; ++q) {
          int tcl = tg * 4 + q;
          acc[q] += w * xin[(3 * tcl + k) * 129 + dcol];
        }
      }
    }
  }
  float ps = 0.f, pss = 0.f;
#pragma unroll
  for (int q = 0; q < 4; ++q) {
    int tcl = tg * 4 + q;
    ws[EMB_OFF + ((size_t)bb * TC_ + tcg * 16 + tcl) * E_ + e] = acc[q];
    ps += acc[q]; pss += acc[q] * acc[q];
  }
  bnr1[tg * 64 + e] = ps;
  bnr2[tg * 64 + e] = pss;
  __syncthreads();
  if (tid < 64) {
    float s1 = bnr1[tid] + bnr1[64 + tid] + bnr1[128 + tid] + bnr1[192 + tid];
    float s2 = bnr2[tid] + bnr2[64 + tid] + bnr2[128 + tid] + bnr2[192 + tid];
    atomicAdd(&ws[SUM_OFF + tid], s1);
    atomicAdd(&ws[SUM_OFF + 64 + tid], s2);
  }
}

// ---------------- BN finalize ----------------
__global__ void bn_finalize_kernel(const float* __restrict__ gamma,
                                   const float* __restrict__ beta,
                                   float* __restrict__ ws) {
  int e = threadIdx.x;
  if (e < 64) {
    const float n = (float)(B_ * TC_);
    float mean = ws[SUM_OFF + e] / n;
    float var = ws[SUM_OFF + 64 + e] / n - mean * mean;
    float sc = gamma[e] * rsqrtf(var + BNEPS);
    ws[SCL_OFF + e] = sc;
    ws[SCL_OFF + 64 + e] = beta[e] - mean * sc;
  }
}

// ---------------- z_x = relu(bn(emb)) @ w_ih^T + b_ih + b_hh ----------------
__global__ __launch_bounds__(256) void zx_kernel(const float* __restrict__ b_ih,
                                                 const float* __restrict__ b_hh,
                                                 float* __restrict__ ws) {
  __shared__ __align__(16) float actT[16 * 64];
  int tid = threadIdx.x;
  int bb = blockIdx.x >> 4, tg2 = blockIdx.x & 15;
  for (int idx = tid; idx < 1024; idx += 256) {
    int tl = idx >> 6, e2 = idx & 63;
    float v = ws[EMB_OFF + ((size_t)bb * TC_ + tg2 * 16 + tl) * E_ + e2];
    actT[idx] = fmaxf(v * ws[SCL_OFF + e2] + ws[SCL_OFF + 64 + e2], 0.f);
  }
  __syncthreads();
  int j0 = tid, j1 = tid + 256;
  float acc0[16], acc1[16];
  float bias0 = b_ih[j0] + b_hh[j0];
  float bias1 = b_ih[j1] + b_hh[j1];
#pragma unroll
  for (int tl = 0; tl < 16; ++tl) { acc0[tl] = bias0; acc1[tl] = bias1; }
  const float* wp = ws + WIH_OFF;
  for (int e4 = 0; e4 < 16; ++e4) {
    float4 w0 = *(const float4*)(wp + ((size_t)e4 * FH_ + j0) * 4);
    float4 w1 = *(const float4*)(wp + ((size_t)e4 * FH_ + j1) * 4);
#pragma unroll
    for (int tl = 0; tl < 16; ++tl) {
      float4 a4 = *(const float4*)(actT + tl * 64 + e4 * 4);
      acc0[tl] += w0.x * a4.x + w0.y * a4.y + w0.z * a4.z + w0.w * a4.w;
      acc1[tl] += w1.x * a4.x + w1.y * a4.y + w1.z * a4.z + w1.w * a4.w;
    }
  }
#pragma unroll
  for (int tl = 0; tl < 16; ++tl) {
    size_t base = ZX_OFF + ((size_t)bb * TC_ + tg2 * 16 + tl) * FH_;
    ws[base + j0] = acc0[tl];
    ws[base + j1] = acc1[tl];
  }
}

// ---------------- Gram tile helper: C tiles via mfma 16x16x32 bf16, split hi/lo ----
template <int NCT>
__device__ inline void gram_do(int rt, int ct0, int lane,
                               const __bf16* GtHi, const __bf16* GtLo,
                               float* M_s, float* y_s) {
  int m = lane & 15, q = lane >> 4;
  floatx4 C[NCT];
#pragma unroll
  for (int ci = 0; ci < NCT; ++ci) C[ci] = (floatx4){0.f, 0.f, 0.f, 0.f};
#pragma unroll
  for (int p = 0; p < 3; ++p) {
    const __bf16* Aa = (p < 2) ? GtHi : GtLo;
    const __bf16* Ba = (p == 1) ? GtLo : GtHi;
    bf16x8 Af[4];
#pragma unroll
    for (int kt = 0; kt < 4; ++kt)
      Af[kt] = *(const bf16x8*)(Aa + (rt * 16 + m) * 136 + kt * 32 + q * 8);
#pragma unroll
    for (int ci = 0; ci < NCT; ++ci) {
#pragma unroll
      for (int kt = 0; kt < 4; ++kt) {
        bf16x8 Bf = *(const bf16x8*)(Ba + ((ct0 + ci) * 16 + m) * 136 + kt * 32 + q * 8);
        C[ci] = __builtin_amdgcn_mfma_f32_16x16x32_bf16(Af[kt], Bf, C[ci], 0, 0, 0);
      }
    }
  }
#pragma unroll
  for (int ci = 0; ci < NCT; ++ci) {
    int ct = ct0 + ci;
#pragma unroll
    for (int reg = 0; reg < 4; ++reg) {
      int grow = rt * 16 + q * 4 + reg;
      if (ct < 4) {
        int gcol = ct * 16 + m;
        M_s[grow * 65 + gcol] = EPSP * C[ci][reg] + ((grow == gcol) ? 1.f : 0.f);
      } else if (m == 0) {
        y_s[grow] = C[ci][reg];   // y = G^T s (unscaled)
      }
    }
  }
}

// ---------------- the sequential ProxLSTM scan: 1 block per batch ----------------
__global__ __launch_bounds__(512, 2) void scan_kernel(const float* __restrict__ w_hh,
                                                      const float* __restrict__ lin_w,
                                                      const float* __restrict__ lin_b,
                                                      const float* __restrict__ ws,
                                                      float* __restrict__ out) {
  // bf16 split-precision staging (stride 136/72 keeps b128 bank distribution even)
  __shared__ __align__(16) __bf16 GtHi[80 * 136], GtLo[80 * 136];   // rows 0-63 = G^T[e][h], row 64 = s, 65-79 = 0
  __shared__ __align__(16) __bf16 GntHi[128 * 72], GntLo[128 * 72]; // G[h][e]
  __shared__ __align__(16) __bf16 BxHi[16 * 72], BxLo[16 * 72];     // row 0 = x, rows 1-15 = 0
  __shared__ float M_s[64 * 65];
  __shared__ float Lp_s[16 * 64];
  __shared__ float z_s[512];
  __shared__ float s_s[128], o_s[128], a1_s[128], a2_s[128], a3_s[128];
  __shared__ __align__(16) float c_s[128], h_s[128];
  __shared__ float y_s[64];

  int tid = threadIdx.x;
  int bb = blockIdx.x;
  int lane = tid & 63;
  int wv = tid >> 6;

  // ---- persistent register caches ----
  // w_hh row for z[tid]: 128 f32 in VGPRs (FULL unroll everywhere -> no scratch)
  float4 w4[32];
  {
    const float4* wr = (const float4*)(w_hh + (size_t)tid * H_);
#pragma unroll
    for (int k = 0; k < 32; ++k) w4[k] = wr[k];
  }
  // w_ih panel for G-build: gates i,f,g, rows h0..h0+7, cols e0,e0+1 (48 f32)
  int hg = tid >> 5, ep = tid & 31;
  int h0 = hg * 8, e0 = ep * 2;
  float WI[2][8], WF[2][8], WG[2][8];
  {
    const float* wt = ws + WT_OFF;
#pragma unroll
    for (int e = 0; e < 2; ++e) {
#pragma unroll
      for (int hf = 0; hf < 2; ++hf) {
        float4 vi = *(const float4*)(wt + (size_t)(e0 + e) * 128 + h0 + hf * 4);
        float4 vf = *(const float4*)(wt + 8192 + (size_t)(e0 + e) * 128 + h0 + hf * 4);
        float4 vg = *(const float4*)(wt + 16384 + (size_t)(e0 + e) * 128 + h0 + hf * 4);
        WI[e][hf * 4 + 0] = vi.x; WI[e][hf * 4 + 1] = vi.y; WI[e][hf * 4 + 2] = vi.z; WI[e][hf * 4 + 3] = vi.w;
        WF[e][hf * 4 + 0] = vf.x; WF[e][hf * 4 + 1] = vf.y; WF[e][hf * 4 + 2] = vf.z; WF[e][hf * 4 + 3] = vf.w;
        WG[e][hf * 4 + 0] = vg.x; WG[e][hf * 4 + 1] = vg.y; WG[e][hf * 4 + 2] = vg.z; WG[e][hf * 4 + 3] = vg.w;
      }
    }
  }

  // ---- zero-init LDS constants ----
  for (int i = tid; i < 15 * 136; i += 512) { GtHi[65 * 136 + i] = (__bf16)0.f; GtLo[65 * 136 + i] = (__bf16)0.f; }
  for (int i = tid; i < 15 * 72; i += 512) { BxHi[72 + i] = (__bf16)0.f; BxLo[72 + i] = (__bf16)0.f; }
  if (tid < 128) { c_s[tid] = 0.f; h_s[tid] = 0.f; }

  const float* zxp = ws + ZX_OFF + (size_t)bb * TC_ * FH_;
  float zx0 = 0.f, zx1 = 0.f, zx2 = 0.f, zx3 = 0.f;
  if (tid < 128) {
    zx0 = zxp[tid]; zx1 = zxp[128 + tid]; zx2 = zxp[256 + tid]; zx3 = zxp[384 + tid];
  }
  float dinv = 1.f;   // wave-0: 1/L[lane][lane]
  __syncthreads();

  for (int t = 0; t < TC_; ++t) {
    // ---- A: z_s[tid] = w_hh[tid,:] . h  (readlane broadcast of h) ----
    {
      float hA = h_s[lane];
      float hB = h_s[64 + lane];
      float acc = 0.f;
#pragma unroll
      for (int k4 = 0; k4 < 32; ++k4) {
        float b0 = (k4 < 16) ? rl(hA, 4 * k4 + 0) : rl(hB, 4 * k4 - 64 + 0);
        float b1 = (k4 < 16) ? rl(hA, 4 * k4 + 1) : rl(hB, 4 * k4 - 64 + 1);
        float b2 = (k4 < 16) ? rl(hA, 4 * k4 + 2) : rl(hB, 4 * k4 - 64 + 2);
        float b3 = (k4 < 16) ? rl(hA, 4 * k4 + 3) : rl(hB, 4 * k4 - 64 + 3);
        acc = fmaf(b0, w4[k4].x, acc);
        acc = fmaf(b1, w4[k4].y, acc);
        acc = fmaf(b2, w4[k4].z, acc);
        acc = fmaf(b3, w4[k4].w, acc);
      }
      z_s[tid] = acc;
    }
    __syncthreads();
    // ---- stage 1 (tid<128): gates, s-row bf16, zx prefetch ----
    if (tid < 128) {
      int h = tid;
      float zi = z_s[h] + zx0, zf = z_s[128 + h] + zx1, zg = z_s[256 + h] + zx2, zo = z_s[384 + h] + zx3;
      float c = c_s[h];
      float ig = fsigmoid(zi);
      float fg = fsigmoid(zf);
      float gg = ftanh(zg);
      float s = fg * c + ig * gg;
      s_s[h] = s;
      o_s[h] = fsigmoid(zo);
      a1_s[h] = ig * (1.f - ig) * gg;
      a2_s[h] = fg * (1.f - fg) * c;
      a3_s[h] = ig * (1.f - gg * gg);
      __bf16 sh = (__bf16)s;
      GtHi[64 * 136 + h] = sh;
      GtLo[64 * 136 + h] = (__bf16)(s - (float)sh);
      if (t + 1 < TC_) {
        const float* zn = zxp + (size_t)(t + 1) * FH_;
        zx0 = zn[h]; zx1 = zn[128 + h]; zx2 = zn[256 + h]; zx3 = zn[384 + h];
      }
    }
    __syncthreads();
    // ---- stage 2 (all): G build -> bf16 split, both layouts ----
    {
      float A1[8], A2[8], A3[8];
      {
        float4 v0 = *(const float4*)(a1_s + h0); float4 v1 = *(const float4*)(a1_s + h0 + 4);
        A1[0] = v0.x; A1[1] = v0.y; A1[2] = v0.z; A1[3] = v0.w;
        A1[4] = v1.x; A1[5] = v1.y; A1[6] = v1.z; A1[7] = v1.w;
        float4 v2 = *(const float4*)(a2_s + h0); float4 v3 = *(const float4*)(a2_s + h0 + 4);
        A2[0] = v2.x; A2[1] = v2.y; A2[2] = v2.z; A2[3] = v2.w;
        A2[4] = v3.x; A2[5] = v3.y; A2[6] = v3.z; A2[7] = v3.w;
        float4 v4 = *(const float4*)(a3_s + h0); float4 v5 = *(const float4*)(a3_s + h0 + 4);
        A3[0] = v4.x; A3[1] = v4.y; A3[2] = v4.z; A3[3] = v4.w;
        A3[4] = v5.x; A3[5] = v5.y; A3[6] = v5.z; A3[7] = v5.w;
      }
      __bf16 ghi[2][8], glo[2][8];
#pragma unroll
      for (int e = 0; e < 2; ++e) {
#pragma unroll
        for (int jj = 0; jj < 8; ++jj) {
          float gv = A1[jj] * WI[e][jj] + A2[jj] * WF[e][jj] + A3[jj] * WG[e][jj];
          __bf16 hi = (__bf16)gv;
          ghi[e][jj] = hi;
          glo[e][jj] = (__bf16)(gv - (float)hi);
        }
      }
#pragma unroll
      for (int jj = 0; jj < 8; ++jj) {
        bf16x2 vh; vh[0] = ghi[0][jj]; vh[1] = ghi[1][jj];
        *(bf16x2*)(&GntHi[(h0 + jj) * 72 + e0]) = vh;
        bf16x2 vl; vl[0] = glo[0][jj]; vl[1] = glo[1][jj];
        *(bf16x2*)(&GntLo[(h0 + jj) * 72 + e0]) = vl;
      }
#pragma unroll
      for (int e = 0; e < 2; ++e) {
        bf16x8 vh, vl;
#pragma unroll
        for (int jj = 0; jj < 8; ++jj) { vh[jj] = ghi[e][jj]; vl[jj] = glo[e][jj]; }
        *(bf16x8*)(&GtHi[(e0 + e) * 136 + h0]) = vh;
        *(bf16x8*)(&GtLo[(e0 + e) * 136 + h0]) = vl;
      }
    }
    __syncthreads();
    // ---- Gram via MFMA: M = I + eps*G^T G ; y = G^T s (col 64) ----
    if (wv < 4) gram_do<3>(wv, 0, lane, GtHi, GtLo, M_s, y_s);
    else        gram_do<2>(wv - 4, 3, lane, GtHi, GtLo, M_s, y_s);
    __syncthreads();
    // ---- D: Cholesky (wave 0, panel-16, readlane pivots) + trailing (8 waves) + solves ----
#pragma unroll 1
    for (int pan = 0; pan < 4; ++pan) {
      int j0 = pan * 16;
      if (tid < 64) {
        float p[16];
#pragma unroll
        for (int jj = 0; jj < 16; ++jj) p[jj] = M_s[lane * 65 + j0 + jj];
#pragma unroll
        for (int jj = 0; jj < 16; ++jj) {
          float d  = rl(p[jj], j0 + jj);
          float rs = frsq(d);
          p[jj] *= rs;                         // diag lane: d*rs = sqrt(d)
          dinv = (lane == j0 + jj) ? rs : dinv;
#pragma unroll
          for (int kk = jj + 1; kk < 16; ++kk) {
            float l = rl(p[jj], j0 + kk);
            p[kk] -= p[jj] * l;
          }
        }
#pragma unroll
        for (int jj = 0; jj < 16; ++jj) {
          M_s[lane * 65 + j0 + jj] = p[jj];
          Lp_s[jj * 64 + lane] = p[jj];
        }
        if (pan == 3) {
          float r = y_s[lane];
          // forward: L y' = y
          for (int i = 0; i < 64; ++i) {
            float Lri = M_s[lane * 65 + i];
            float vv  = rl(r, i) * rl(dinv, i);
            float upd = r - Lri * vv;
            r = (lane == i) ? vv : ((lane > i) ? upd : r);
          }
          // backward: L^T x = y'
          for (int i = 63; i >= 0; --i) {
            float Lil = M_s[i * 65 + lane];
            float vv  = rl(r, i) * rl(dinv, i);
            float upd = r - Lil * vv;
            r = (lane == i) ? vv : ((lane < i) ? upd : r);
          }
          __bf16 xh = (__bf16)r;
          BxHi[lane] = xh;
          BxLo[lane] = (__bf16)(r - (float)xh);
        }
      }
      __syncthreads();
      if (pan < 3) {
        float Lrow[16];
#pragma unroll
        for (int jj = 0; jj < 16; ++jj) Lrow[jj] = Lp_s[jj * 64 + lane];
        for (int k = j0 + 16 + wv; k < 64; k += 8) {
          float acc = M_s[lane * 65 + k];
#pragma unroll
          for (int jj = 0; jj < 16; ++jj) acc -= Lrow[jj] * Lp_s[jj * 64 + k];
          M_s[lane * 65 + k] = acc;
        }
        __syncthreads();
      }
    }
    // ---- E: u = G x via MFMA; c,h update on col-0 lanes ----
    {
      int m = lane & 15, q = lane >> 4;
      floatx4 C = (floatx4){0.f, 0.f, 0.f, 0.f};
#pragma unroll
      for (int p = 0; p < 3; ++p) {
        const __bf16* Aa = (p < 2) ? GntHi : GntLo;
        const __bf16* Ba = (p == 1) ? BxLo : BxHi;
#pragma unroll
        for (int kt = 0; kt < 2; ++kt) {
          bf16x8 Af = *(const bf16x8*)(Aa + (wv * 16 + m) * 72 + kt * 32 + q * 8);
          bf16x8 Bf = *(const bf16x8*)(Ba + m * 72 + kt * 32 + q * 8);
          C = __builtin_amdgcn_mfma_f32_16x16x32_bf16(Af, Bf, C, 0, 0, 0);
        }
      }
      if (m == 0) {
#pragma unroll
        for (int reg = 0; reg < 4; ++reg) {
          int grow = wv * 16 + q * 4 + reg;
          float u  = C[reg];
          float cn = s_s[grow] - EPSP * u;
          float hn = o_s[grow] * ftanh(cn);
          c_s[grow] = cn;
          h_s[grow] = hn;
        }
      }
    }
    __syncthreads();
  }
  // ---- head ----
  if (tid < O_) {
    float acc = lin_b[tid];
    for (int hh2 = 0; hh2 < 128; ++hh2) acc += h_s[hh2] * lin_w[tid * 128 + hh2];
    out[(size_t)bb * O_ + tid] = acc;
  }
}

// ---------------- launch ----------------
extern "C" void kernel_launch(void* const* d_in, const int* in_sizes, int n_in,
                              void* d_out, int out_size, void* d_ws, size_t ws_size,
                              hipStream_t stream) {
  (void)in_sizes; (void)n_in; (void)out_size;
  const float* inputs  = (const float*)d_in[0];
  const float* conv_w  = (const float*)d_in[2];
  const float* conv_b  = (const float*)d_in[3];
  const float* gamma   = (const float*)d_in[4];
  const float* beta    = (const float*)d_in[5];
  const float* w_ih    = (const float*)d_in[6];
  const float* w_hh    = (const float*)d_in[7];
  const float* b_ih    = (const float*)d_in[8];
  const float* b_hh    = (const float*)d_in[9];
  const float* lin_w   = (const float*)d_in[10];
  const float* lin_b   = (const float*)d_in[11];
  float* out = (float*)d_out;
  float* ws  = (float*)d_ws;

  if (ws_size < WS_FLOATS * sizeof(float)) return;

  hipLaunchKernelGGL(prep_kernel, dim3(192), dim3(256), 0, stream, conv_w, w_ih, ws);
  hipLaunchKernelGGL(conv_bn_kernel, dim3(1024), dim3(256), 0, stream, inputs, conv_b, ws);
  hipLaunchKernelGGL(bn_finalize_kernel, dim3(1), dim3(64), 0, stream, gamma, beta, ws);
  hipLaunchKernelGGL(zx_kernel, dim3(1024), dim3(256), 0, stream, b_ih, b_hh, ws);
  hipLaunchKernelGGL(scan_kernel, dim3(64), dim3(512), 0, stream, w_hh, lin_w, lin_b, ws, out);
}

// Round 4
// 6370.140 us; speedup vs baseline: 1.6897x; 1.0129x over previous
//
#include <hip/hip_runtime.h>
#include <math.h>

// ---------------- problem constants ----------------
#define EPSP 5.0f
#define BNEPS 1e-5f
constexpr int B_  = 64;    // batch
constexpr int T_  = 768;   // timesteps in
constexpr int D_  = 128;   // input feature
constexpr int E_  = 64;    // embedding (conv out channels)
constexpr int H_  = 128;   // hidden
constexpr int FH_ = 512;   // 4*H
constexpr int TC_ = 256;   // conv output steps
constexpr int O_  = 10;    // output classes

// ---------------- workspace layout (floats) ----------------
constexpr size_t EMB_OFF = 0;                                   // B*TC*E   [b][tc][e]
constexpr size_t SUM_OFF = EMB_OFF + (size_t)B_ * TC_ * E_;     // 128  (sum[64], ssq[64])
constexpr size_t SCL_OFF = SUM_OFF + 128;                       // 128  (scale[64], shift[64])
constexpr size_t WT_OFF  = SCL_OFF + 128;                       // 24576: w_ih transposed [gate(i,f,g)][e][j]
constexpr size_t WIH_OFF = WT_OFF + (size_t)FH_ * H_;           // 32768  packed [e4][j][4] (zx_kernel)
constexpr size_t CWT_OFF = WIH_OFF + (size_t)FH_ * E_;          // 24576  [k][d][e]
constexpr size_t ZX_OFF  = CWT_OFF + (size_t)E_ * D_ * 3;       // B*TC*FH [b][t][j]
constexpr size_t WS_FLOATS = ZX_OFF + (size_t)B_ * TC_ * FH_;

typedef __bf16 bf16x8 __attribute__((ext_vector_type(8)));
typedef __bf16 bf16x2 __attribute__((ext_vector_type(2)));
typedef float  floatx4 __attribute__((ext_vector_type(4)));

__device__ inline float fast_rcp(float x) {
#if __has_builtin(__builtin_amdgcn_rcpf)
  return __builtin_amdgcn_rcpf(x);
#else
  return 1.0f / x;
#endif
}
__device__ inline float frsq(float x) {
#if __has_builtin(__builtin_amdgcn_rsqf)
  return __builtin_amdgcn_rsqf(x);
#else
  return rsqrtf(x);
#endif
}
__device__ inline float fexp2(float x) {
#if __has_builtin(__builtin_amdgcn_exp2f)
  return __builtin_amdgcn_exp2f(x);
#else
  return exp2f(x);
#endif
}
__device__ inline float rl(float v, int lane) {
  return __int_as_float(__builtin_amdgcn_readlane(__float_as_int(v), lane));
}
#define LOG2E 1.4426950408889634f
__device__ inline float fsigmoid(float x) {
  return fast_rcp(1.f + fexp2(-LOG2E * x));
}
__device__ inline float ftanh(float x) {
  return 1.f - 2.f * fast_rcp(1.f + fexp2(2.f * LOG2E * x));
}

// ---------------- prep: weight repack + zero BN sums ----------------
__global__ void prep_kernel(const float* __restrict__ conv_w,
                            const float* __restrict__ w_ih,
                            float* __restrict__ ws) {
  int gid = blockIdx.x * blockDim.x + threadIdx.x;
  int nthr = gridDim.x * blockDim.x;
  for (int i = gid; i < 128; i += nthr) ws[SUM_OFF + i] = 0.f;
  // w_ih [512][64] -> packed [16][512][4]  (zx_kernel)
  for (int s = gid; s < FH_ * E_; s += nthr) {
    int j = s >> 6, e = s & 63;
    ws[WIH_OFF + ((size_t)(e >> 2) * FH_ + j) * 4 + (e & 3)] = w_ih[s];
  }
  // w_ih gates i,f,g transposed: Wt[g][e][j] = w_ih[(g*128+j)*64+e]  (scan G-build)
  for (int s = gid; s < 3 * H_ * E_ * 2; s += nthr) {   // 3*64*128 = 24576
    int g = s >> 13; int r = s & 8191; int e = r >> 7; int j = r & 127;
    ws[WT_OFF + s] = w_ih[((size_t)(g * 128 + j)) * 64 + e];
  }
  // conv_w [e][d][k] -> [k][d][e]
  for (int s = gid; s < E_ * D_ * 3; s += nthr) {
    int e = s / 384; int r = s - e * 384; int d = r / 3; int k = r - d * 3;
    ws[CWT_OFF + ((size_t)k * D_ + d) * E_ + e] = conv_w[s];
  }
}

// ---------------- conv + L2-normalize + BN partial sums ----------------
__global__ __launch_bounds__(256) void conv_bn_kernel(const float* __restrict__ inputs,
                                                      const float* __restrict__ conv_b,
                                                      float* __restrict__ ws) {
  __shared__ float xin[48 * 129];
  __shared__ float rnorm[48];
  __shared__ float cwc[3 * 16 * 64];
  __shared__ float bnr1[256], bnr2[256];
  int tid = threadIdx.x;
  int bb = blockIdx.x >> 4, tcg = blockIdx.x & 15;
  const float* inp = inputs + ((size_t)bb * T_ + (size_t)tcg * 48) * D_;
  for (int idx = tid; idx < 48 * 128; idx += 256) {
    int r = idx >> 7, d = idx & 127;
    xin[r * 129 + d] = inp[idx];
  }
  __syncthreads();
  if (tid < 48) {
    float ss = 0.f;
    for (int d = 0; d < 128; ++d) { float v = xin[tid * 129 + d]; ss += v * v; }
    rnorm[tid] = 1.0f / fmaxf(sqrtf(ss), 1e-12f);
  }
  __syncthreads();
  for (int idx = tid; idx < 48 * 128; idx += 256) {
    int r = idx >> 7, d = idx & 127;
    xin[r * 129 + d] *= rnorm[r];
  }
  int e = tid & 63, tg = tid >> 6;
  float cb = conv_b[e];
  float acc[4];
#pragma unroll
  for (int q = 0; q < 4; ++q) acc[q] = cb;
  for (int ch = 0; ch < 8; ++ch) {
    __syncthreads();
    for (int idx = tid; idx < 3072; idx += 256) {
      int k = idx >> 10; int i2 = idx & 1023; int dd = i2 >> 6; int e2 = i2 & 63;
      cwc[idx] = ws[CWT_OFF + ((size_t)k * D_ + ch * 16 + dd) * E_ + e2];
    }
    __syncthreads();
    for (int dd = 0; dd < 16; ++dd) {
      int dcol = ch * 16 + dd;
#pragma unroll
      for (int k = 0; k < 3; ++k) {
        float w = cwc[(k * 16 + dd) * 64 + e];
#pragma unroll
        for (int q = 0; q < 4; ++q) {
          int tcl = tg * 4 + q;
          acc[q] += w * xin[(3 * tcl + k) * 129 + dcol];
        }
      }
    }
  }
  float ps = 0.f, pss = 0.f;
#pragma unroll
  for (int q = 0; q < 4; ++q) {
    int tcl = tg * 4 + q;
    ws[EMB_OFF + ((size_t)bb * TC_ + tcg * 16 + tcl) * E_ + e] = acc[q];
    ps += acc[q]; pss += acc[q] * acc[q];
  }
  bnr1[tg * 64 + e] = ps;
  bnr2[tg * 64 + e] = pss;
  __syncthreads();
  if (tid < 64) {
    float s1 = bnr1[tid] + bnr1[64 + tid] + bnr1[128 + tid] + bnr1[192 + tid];
    float s2 = bnr2[tid] + bnr2[64 + tid] + bnr2[128 + tid] + bnr2[192 + tid];
    atomicAdd(&ws[SUM_OFF + tid], s1);
    atomicAdd(&ws[SUM_OFF + 64 + tid], s2);
  }
}

// ---------------- BN finalize ----------------
__global__ void bn_finalize_kernel(const float* __restrict__ gamma,
                                   const float* __restrict__ beta,
                                   float* __restrict__ ws) {
  int e = threadIdx.x;
  if (e < 64) {
    const float n = (float)(B_ * TC_);
    float mean = ws[SUM_OFF + e] / n;
    float var = ws[SUM_OFF + 64 + e] / n - mean * mean;
    float sc = gamma[e] * rsqrtf(var + BNEPS);
    ws[SCL_OFF + e] = sc;
    ws[SCL_OFF + 64 + e] = beta[e] - mean * sc;
  }
}

// ---------------- z_x = relu(bn(emb)) @ w_ih^T + b_ih + b_hh ----------------
__global__ __launch_bounds__(256) void zx_kernel(const float* __restrict__ b_ih,
                                                 const float* __restrict__ b_hh,
                                                 float* __restrict__ ws) {
  __shared__ __align__(16) float actT[16 * 64];
  int tid = threadIdx.x;
  int bb = blockIdx.x >> 4, tg2 = blockIdx.x & 15;
  for (int idx = tid; idx < 1024; idx += 256) {
    int tl = idx >> 6, e2 = idx & 63;
    float v = ws[EMB_OFF + ((size_t)bb * TC_ + tg2 * 16 + tl) * E_ + e2];
    actT[idx] = fmaxf(v * ws[SCL_OFF + e2] + ws[SCL_OFF + 64 + e2], 0.f);
  }
  __syncthreads();
  int j0 = tid, j1 = tid + 256;
  float acc0[16], acc1[16];
  float bias0 = b_ih[j0] + b_hh[j0];
  float bias1 = b_ih[j1] + b_hh[j1];
#pragma unroll
  for (int tl = 0; tl < 16; ++tl) { acc0[tl] = bias0; acc1[tl] = bias1; }
  const float* wp = ws + WIH_OFF;
  for (int e4 = 0; e4 < 16; ++e4) {
    float4 w0 = *(const float4*)(wp + ((size_t)e4 * FH_ + j0) * 4);
    float4 w1 = *(const float4*)(wp + ((size_t)e4 * FH_ + j1) * 4);
#pragma unroll
    for (int tl = 0; tl < 16; ++tl) {
      float4 a4 = *(const float4*)(actT + tl * 64 + e4 * 4);
      acc0[tl] += w0.x * a4.x + w0.y * a4.y + w0.z * a4.z + w0.w * a4.w;
      acc1[tl] += w1.x * a4.x + w1.y * a4.y + w1.z * a4.z + w1.w * a4.w;
    }
  }
#pragma unroll
  for (int tl = 0; tl < 16; ++tl) {
    size_t base = ZX_OFF + ((size_t)bb * TC_ + tg2 * 16 + tl) * FH_;
    ws[base + j0] = acc0[tl];
    ws[base + j1] = acc1[tl];
  }
}

// ---------------- Gram tile helper: C tiles via mfma 16x16x32 bf16, split hi/lo ----
template <int NCT>
__device__ inline void gram_do(int rt, int ct0, int lane,
                               const __bf16* GtHi, const __bf16* GtLo,
                               float* M_s, float* y_s) {
  int m = lane & 15, q = lane >> 4;
  floatx4 C[NCT];
#pragma unroll
  for (int ci = 0; ci < NCT; ++ci) C[ci] = (floatx4){0.f, 0.f, 0.f, 0.f};
#pragma unroll
  for (int p = 0; p < 3; ++p) {
    const __bf16* Aa = (p < 2) ? GtHi : GtLo;
    const __bf16* Ba = (p == 1) ? GtLo : GtHi;
    bf16x8 Af[4];
#pragma unroll
    for (int kt = 0; kt < 4; ++kt)
      Af[kt] = *(const bf16x8*)(Aa + (rt * 16 + m) * 136 + kt * 32 + q * 8);
#pragma unroll
    for (int ci = 0; ci < NCT; ++ci) {
#pragma unroll
      for (int kt = 0; kt < 4; ++kt) {
        bf16x8 Bf = *(const bf16x8*)(Ba + ((ct0 + ci) * 16 + m) * 136 + kt * 32 + q * 8);
        C[ci] = __builtin_amdgcn_mfma_f32_16x16x32_bf16(Af[kt], Bf, C[ci], 0, 0, 0);
      }
    }
  }
#pragma unroll
  for (int ci = 0; ci < NCT; ++ci) {
    int ct = ct0 + ci;
#pragma unroll
    for (int reg = 0; reg < 4; ++reg) {
      int grow = rt * 16 + q * 4 + reg;
      if (ct < 4) {
        int gcol = ct * 16 + m;
        M_s[grow * 65 + gcol] = EPSP * C[ci][reg] + ((grow == gcol) ? 1.f : 0.f);
      } else if (m == 0) {
        y_s[grow] = C[ci][reg];   // y = G^T s (unscaled)
      }
    }
  }
}

// ---------------- the sequential ProxLSTM scan: 1 block per batch ----------------
// LDS (109 KB) already caps occupancy at 1 block/CU, so request the full 256-VGPR
// budget (min-waves=1): the 176-reg persistent weight cache must NOT spill.
__global__ __launch_bounds__(512, 1) void scan_kernel(const float* __restrict__ w_hh,
                                                      const float* __restrict__ lin_w,
                                                      const float* __restrict__ lin_b,
                                                      const float* __restrict__ ws,
                                                      float* __restrict__ out) {
  // bf16 split-precision staging (stride 136/72 keeps b128 bank distribution even)
  __shared__ __align__(16) __bf16 GtHi[80 * 136], GtLo[80 * 136];   // rows 0-63 = G^T[e][h], row 64 = s, 65-79 = 0
  __shared__ __align__(16) __bf16 GntHi[128 * 72], GntLo[128 * 72]; // G[h][e]
  __shared__ __align__(16) __bf16 BxHi[16 * 72], BxLo[16 * 72];     // row 0 = x, rows 1-15 = 0
  __shared__ float M_s[64 * 65];
  __shared__ float Lp_s[16 * 64];
  __shared__ float z_s[512];
  __shared__ float s_s[128], o_s[128], a1_s[128], a2_s[128], a3_s[128];
  __shared__ __align__(16) float c_s[128], h_s[128];
  __shared__ float y_s[64];

  int tid = threadIdx.x;
  int bb = blockIdx.x;
  int lane = tid & 63;
  int wv = tid >> 6;

  // ---- persistent register caches ----
  // w_hh row for z[tid]: 128 f32 in VGPRs
  float4 w4[32];
  {
    const float4* wr = (const float4*)(w_hh + (size_t)tid * H_);
#pragma unroll
    for (int k = 0; k < 32; ++k) w4[k] = wr[k];
  }
  // w_ih panel for G-build: gates i,f,g, rows h0..h0+7, cols e0,e0+1 (48 f32)
  int hg = tid >> 5, ep = tid & 31;
  int h0 = hg * 8, e0 = ep * 2;
  float WI[2][8], WF[2][8], WG[2][8];
  {
    const float* wt = ws + WT_OFF;
#pragma unroll
    for (int e = 0; e < 2; ++e) {
#pragma unroll
      for (int hf = 0; hf < 2; ++hf) {
        float4 vi = *(const float4*)(wt + (size_t)(e0 + e) * 128 + h0 + hf * 4);
        float4 vf = *(const float4*)(wt + 8192 + (size_t)(e0 + e) * 128 + h0 + hf * 4);
        float4 vg = *(const float4*)(wt + 16384 + (size_t)(e0 + e) * 128 + h0 + hf * 4);
        WI[e][hf * 4 + 0] = vi.x; WI[e][hf * 4 + 1] = vi.y; WI[e][hf * 4 + 2] = vi.z; WI[e][hf * 4 + 3] = vi.w;
        WF[e][hf * 4 + 0] = vf.x; WF[e][hf * 4 + 1] = vf.y; WF[e][hf * 4 + 2] = vf.z; WF[e][hf * 4 + 3] = vf.w;
        WG[e][hf * 4 + 0] = vg.x; WG[e][hf * 4 + 1] = vg.y; WG[e][hf * 4 + 2] = vg.z; WG[e][hf * 4 + 3] = vg.w;
      }
    }
  }

  // ---- zero-init LDS constants ----
  for (int i = tid; i < 15 * 136; i += 512) { GtHi[65 * 136 + i] = (__bf16)0.f; GtLo[65 * 136 + i] = (__bf16)0.f; }
  for (int i = tid; i < 15 * 72; i += 512) { BxHi[72 + i] = (__bf16)0.f; BxLo[72 + i] = (__bf16)0.f; }
  if (tid < 128) { c_s[tid] = 0.f; h_s[tid] = 0.f; }

  const float* zxp = ws + ZX_OFF + (size_t)bb * TC_ * FH_;
  float zx0 = 0.f, zx1 = 0.f, zx2 = 0.f, zx3 = 0.f;
  if (tid < 128) {
    zx0 = zxp[tid]; zx1 = zxp[128 + tid]; zx2 = zxp[256 + tid]; zx3 = zxp[384 + tid];
  }
  float dinv = 1.f;   // wave-0: 1/L[lane][lane]
  __syncthreads();

  for (int t = 0; t < TC_; ++t) {
    // ---- A: z_s[tid] = w_hh[tid,:] . h  (readlane broadcast of h) ----
    {
      float hA = h_s[lane];
      float hB = h_s[64 + lane];
      float acc = 0.f;
#pragma unroll
      for (int k4 = 0; k4 < 32; ++k4) {
        float b0 = (k4 < 16) ? rl(hA, 4 * k4 + 0) : rl(hB, 4 * k4 - 64 + 0);
        float b1 = (k4 < 16) ? rl(hA, 4 * k4 + 1) : rl(hB, 4 * k4 - 64 + 1);
        float b2 = (k4 < 16) ? rl(hA, 4 * k4 + 2) : rl(hB, 4 * k4 - 64 + 2);
        float b3 = (k4 < 16) ? rl(hA, 4 * k4 + 3) : rl(hB, 4 * k4 - 64 + 3);
        acc = fmaf(b0, w4[k4].x, acc);
        acc = fmaf(b1, w4[k4].y, acc);
        acc = fmaf(b2, w4[k4].z, acc);
        acc = fmaf(b3, w4[k4].w, acc);
      }
      z_s[tid] = acc;
    }
    __syncthreads();
    // ---- stage 1 (tid<128): gates, s-row bf16, zx prefetch ----
    if (tid < 128) {
      int h = tid;
      float zi = z_s[h] + zx0, zf = z_s[128 + h] + zx1, zg = z_s[256 + h] + zx2, zo = z_s[384 + h] + zx3;
      float c = c_s[h];
      float ig = fsigmoid(zi);
      float fg = fsigmoid(zf);
      float gg = ftanh(zg);
      float s = fg * c + ig * gg;
      s_s[h] = s;
      o_s[h] = fsigmoid(zo);
      a1_s[h] = ig * (1.f - ig) * gg;
      a2_s[h] = fg * (1.f - fg) * c;
      a3_s[h] = ig * (1.f - gg * gg);
      __bf16 sh = (__bf16)s;
      GtHi[64 * 136 + h] = sh;
      GtLo[64 * 136 + h] = (__bf16)(s - (float)sh);
      if (t + 1 < TC_) {
        const float* zn = zxp + (size_t)(t + 1) * FH_;
        zx0 = zn[h]; zx1 = zn[128 + h]; zx2 = zn[256 + h]; zx3 = zn[384 + h];
      }
    }
    __syncthreads();
    // ---- stage 2 (all): G build -> bf16 split, both layouts ----
    {
      float A1[8], A2[8], A3[8];
      {
        float4 v0 = *(const float4*)(a1_s + h0); float4 v1 = *(const float4*)(a1_s + h0 + 4);
        A1[0] = v0.x; A1[1] = v0.y; A1[2] = v0.z; A1[3] = v0.w;
        A1[4] = v1.x; A1[5] = v1.y; A1[6] = v1.z; A1[7] = v1.w;
        float4 v2 = *(const float4*)(a2_s + h0); float4 v3 = *(const float4*)(a2_s + h0 + 4);
        A2[0] = v2.x; A2[1] = v2.y; A2[2] = v2.z; A2[3] = v2.w;
        A2[4] = v3.x; A2[5] = v3.y; A2[6] = v3.z; A2[7] = v3.w;
        float4 v4 = *(const float4*)(a3_s + h0); float4 v5 = *(const float4*)(a3_s + h0 + 4);
        A3[0] = v4.x; A3[1] = v4.y; A3[2] = v4.z; A3[3] = v4.w;
        A3[4] = v5.x; A3[5] = v5.y; A3[6] = v5.z; A3[7] = v5.w;
      }
      __bf16 ghi[2][8], glo[2][8];
#pragma unroll
      for (int e = 0; e < 2; ++e) {
#pragma unroll
        for (int jj = 0; jj < 8; ++jj) {
          float gv = A1[jj] * WI[e][jj] + A2[jj] * WF[e][jj] + A3[jj] * WG[e][jj];
          __bf16 hi = (__bf16)gv;
          ghi[e][jj] = hi;
          glo[e][jj] = (__bf16)(gv - (float)hi);
        }
      }
#pragma unroll
      for (int jj = 0; jj < 8; ++jj) {
        bf16x2 vh; vh[0] = ghi[0][jj]; vh[1] = ghi[1][jj];
        *(bf16x2*)(&GntHi[(h0 + jj) * 72 + e0]) = vh;
        bf16x2 vl; vl[0] = glo[0][jj]; vl[1] = glo[1][jj];
        *(bf16x2*)(&GntLo[(h0 + jj) * 72 + e0]) = vl;
      }
#pragma unroll
      for (int e = 0; e < 2; ++e) {
        bf16x8 vh, vl;
#pragma unroll
        for (int jj = 0; jj < 8; ++jj) { vh[jj] = ghi[e][jj]; vl[jj] = glo[e][jj]; }
        *(bf16x8*)(&GtHi[(e0 + e) * 136 + h0]) = vh;
        *(bf16x8*)(&GtLo[(e0 + e) * 136 + h0]) = vl;
      }
    }
    __syncthreads();
    // ---- Gram via MFMA: M = I + eps*G^T G ; y = G^T s (col 64) ----
    if (wv < 4) gram_do<3>(wv, 0, lane, GtHi, GtLo, M_s, y_s);
    else        gram_do<2>(wv - 4, 3, lane, GtHi, GtLo, M_s, y_s);
    __syncthreads();
    // ---- D: Cholesky (wave 0, panel-16, readlane pivots) + trailing (8 waves) + solves ----
#pragma unroll 1
    for (int pan = 0; pan < 4; ++pan) {
      int j0 = pan * 16;
      if (tid < 64) {
        float p[16];
#pragma unroll
        for (int jj = 0; jj < 16; ++jj) p[jj] = M_s[lane * 65 + j0 + jj];
#pragma unroll
        for (int jj = 0; jj < 16; ++jj) {
          float d  = rl(p[jj], j0 + jj);
          float rs = frsq(d);
          p[jj] *= rs;                         // diag lane: d*rs = sqrt(d)
          dinv = (lane == j0 + jj) ? rs : dinv;
#pragma unroll
          for (int kk = jj + 1; kk < 16; ++kk) {
            float l = rl(p[jj], j0 + kk);
            p[kk] -= p[jj] * l;
          }
        }
#pragma unroll
        for (int jj = 0; jj < 16; ++jj) {
          M_s[lane * 65 + j0 + jj] = p[jj];
          Lp_s[jj * 64 + lane] = p[jj];
        }
        if (pan == 3) {
          float r = y_s[lane];
          // forward: L y' = y
#pragma unroll 16
          for (int i = 0; i < 64; ++i) {
            float Lri = M_s[lane * 65 + i];
            float vv  = rl(r, i) * rl(dinv, i);
            float upd = r - Lri * vv;
            r = (lane == i) ? vv : ((lane > i) ? upd : r);
          }
          // backward: L^T x = y'
#pragma unroll 16
          for (int i = 63; i >= 0; --i) {
            float Lil = M_s[i * 65 + lane];
            float vv  = rl(r, i) * rl(dinv, i);
            float upd = r - Lil * vv;
            r = (lane == i) ? vv : ((lane < i) ? upd : r);
          }
          __bf16 xh = (__bf16)r;
          BxHi[lane] = xh;
          BxLo[lane] = (__bf16)(r - (float)xh);
        }
      }
      __syncthreads();
      if (pan < 3) {
        float Lrow[16];
#pragma unroll
        for (int jj = 0; jj < 16; ++jj) Lrow[jj] = Lp_s[jj * 64 + lane];
        for (int k = j0 + 16 + wv; k < 64; k += 8) {
          float acc = M_s[lane * 65 + k];
#pragma unroll
          for (int jj = 0; jj < 16; ++jj) acc -= Lrow[jj] * Lp_s[jj * 64 + k];
          M_s[lane * 65 + k] = acc;
        }
        __syncthreads();
      }
    }
    // ---- E: u = G x via MFMA; c,h update on col-0 lanes ----
    {
      int m = lane & 15, q = lane >> 4;
      floatx4 C = (floatx4){0.f, 0.f, 0.f, 0.f};
#pragma unroll
      for (int p = 0; p < 3; ++p) {
        const __bf16* Aa = (p < 2) ? GntHi : GntLo;
        const __bf16* Ba = (p == 1) ? BxLo : BxHi;
#pragma unroll
        for (int kt = 0; kt < 2; ++kt) {
          bf16x8 Af = *(const bf16x8*)(Aa + (wv * 16 + m) * 72 + kt * 32 + q * 8);
          bf16x8 Bf = *(const bf16x8*)(Ba + m * 72 + kt * 32 + q * 8);
          C = __builtin_amdgcn_mfma_f32_16x16x32_bf16(Af, Bf, C, 0, 0, 0);
        }
      }
      if (m == 0) {
#pragma unroll
        for (int reg = 0; reg < 4; ++reg) {
          int grow = wv * 16 + q * 4 + reg;
          float u  = C[reg];
          float cn = s_s[grow] - EPSP * u;
          float hn = o_s[grow] * ftanh(cn);
          c_s[grow] = cn;
          h_s[grow] = hn;
        }
      }
    }
    __syncthreads();
  }
  // ---- head ----
  if (tid < O_) {
    float acc = lin_b[tid];
    for (int hh2 = 0; hh2 < 128; ++hh2) acc += h_s[hh2] * lin_w[tid * 128 + hh2];
    out[(size_t)bb * O_ + tid] = acc;
  }
}

// ---------------- launch ----------------
extern "C" void kernel_launch(void* const* d_in, const int* in_sizes, int n_in,
                              void* d_out, int out_size, void* d_ws, size_t ws_size,
                              hipStream_t stream) {
  (void)in_sizes; (void)n_in; (void)out_size;
  const float* inputs  = (const float*)d_in[0];
  const float* conv_w  = (const float*)d_in[2];
  const float* conv_b  = (const float*)d_in[3];
  const float* gamma   = (const float*)d_in[4];
  const float* beta    = (const float*)d_in[5];
  const float* w_ih    = (const float*)d_in[6];
  const float* w_hh    = (const float*)d_in[7];
  const float* b_ih    = (const float*)d_in[8];
  const float* b_hh    = (const float*)d_in[9];
  const float* lin_w   = (const float*)d_in[10];
  const float* lin_b   = (const float*)d_in[11];
  float* out = (float*)d_out;
  float* ws  = (float*)d_ws;

  if (ws_size < WS_FLOATS * sizeof(float)) return;

  hipLaunchKernelGGL(prep_kernel, dim3(192), dim3(256), 0, stream, conv_w, w_ih, ws);
  hipLaunchKernelGGL(conv_bn_kernel, dim3(1024), dim3(256), 0, stream, inputs, conv_b, ws);
  hipLaunchKernelGGL(bn_finalize_kernel, dim3(1), dim3(64), 0, stream, gamma, beta, ws);
  hipLaunchKernelGGL(zx_kernel, dim3(1024), dim3(256), 0, stream, b_ih, b_hh, ws);
  hipLaunchKernelGGL(scan_kernel, dim3(64), dim3(512), 0, stream, w_hh, lin_w, lin_b, ws, out);
}

// Round 5
// 6346.682 us; speedup vs baseline: 1.6959x; 1.0037x over previous
//
#include <hip/hip_runtime.h>
#include <math.h>

// ---------------- problem constants ----------------
#define EPSP 5.0f
#define BNEPS 1e-5f
constexpr int B_  = 64;    // batch
constexpr int T_  = 768;   // timesteps in
constexpr int D_  = 128;   // input feature
constexpr int E_  = 64;    // embedding (conv out channels)
constexpr int H_  = 128;   // hidden
constexpr int FH_ = 512;   // 4*H
constexpr int TC_ = 256;   // conv output steps
constexpr int O_  = 10;    // output classes

// ---------------- workspace layout (floats) ----------------
constexpr size_t EMB_OFF = 0;                                   // B*TC*E   [b][tc][e]
constexpr size_t SUM_OFF = EMB_OFF + (size_t)B_ * TC_ * E_;     // 128  (sum[64], ssq[64])
constexpr size_t SCL_OFF = SUM_OFF + 128;                       // 128  (scale[64], shift[64])
constexpr size_t WT_OFF  = SCL_OFF + 128;                       // 24576: w_ih transposed [gate(i,f,g)][e][j]
constexpr size_t WIH_OFF = WT_OFF + (size_t)FH_ * H_;           // 32768  packed [e4][j][4] (zx_kernel)
constexpr size_t CWT_OFF = WIH_OFF + (size_t)FH_ * E_;          // 24576  [k][d][e]
constexpr size_t ZX_OFF  = CWT_OFF + (size_t)E_ * D_ * 3;       // B*TC*FH [b][t][j]
constexpr size_t WS_FLOATS = ZX_OFF + (size_t)B_ * TC_ * FH_;

typedef __bf16 bf16x8 __attribute__((ext_vector_type(8)));
typedef __bf16 bf16x2 __attribute__((ext_vector_type(2)));
typedef float  floatx4 __attribute__((ext_vector_type(4)));

__device__ inline float fast_rcp(float x) {
#if __has_builtin(__builtin_amdgcn_rcpf)
  return __builtin_amdgcn_rcpf(x);
#else
  return 1.0f / x;
#endif
}
__device__ inline float frsq(float x) {
#if __has_builtin(__builtin_amdgcn_rsqf)
  return __builtin_amdgcn_rsqf(x);
#else
  return rsqrtf(x);
#endif
}
__device__ inline float fexp2(float x) {
#if __has_builtin(__builtin_amdgcn_exp2f)
  return __builtin_amdgcn_exp2f(x);
#else
  return exp2f(x);
#endif
}
__device__ inline float rl(float v, int lane) {
  return __int_as_float(__builtin_amdgcn_readlane(__float_as_int(v), lane));
}
#define LOG2E 1.4426950408889634f
__device__ inline float fsigmoid(float x) {
  return fast_rcp(1.f + fexp2(-LOG2E * x));
}
__device__ inline float ftanh(float x) {
  return 1.f - 2.f * fast_rcp(1.f + fexp2(2.f * LOG2E * x));
}

// ---------------- prep: weight repack + zero BN sums ----------------
__global__ void prep_kernel(const float* __restrict__ conv_w,
                            const float* __restrict__ w_ih,
                            float* __restrict__ ws) {
  int gid = blockIdx.x * blockDim.x + threadIdx.x;
  int nthr = gridDim.x * blockDim.x;
  for (int i = gid; i < 128; i += nthr) ws[SUM_OFF + i] = 0.f;
  // w_ih [512][64] -> packed [16][512][4]  (zx_kernel)
  for (int s = gid; s < FH_ * E_; s += nthr) {
    int j = s >> 6, e = s & 63;
    ws[WIH_OFF + ((size_t)(e >> 2) * FH_ + j) * 4 + (e & 3)] = w_ih[s];
  }
  // w_ih gates i,f,g transposed: Wt[g][e][j] = w_ih[(g*128+j)*64+e]  (scan G-build)
  for (int s = gid; s < 3 * H_ * E_ * 2; s += nthr) {   // 3*64*128 = 24576
    int g = s >> 13; int r = s & 8191; int e = r >> 7; int j = r & 127;
    ws[WT_OFF + s] = w_ih[((size_t)(g * 128 + j)) * 64 + e];
  }
  // conv_w [e][d][k] -> [k][d][e]
  for (int s = gid; s < E_ * D_ * 3; s += nthr) {
    int e = s / 384; int r = s - e * 384; int d = r / 3; int k = r - d * 3;
    ws[CWT_OFF + ((size_t)k * D_ + d) * E_ + e] = conv_w[s];
  }
}

// ---------------- conv + L2-normalize + BN partial sums ----------------
__global__ __launch_bounds__(256) void conv_bn_kernel(const float* __restrict__ inputs,
                                                      const float* __restrict__ conv_b,
                                                      float* __restrict__ ws) {
  __shared__ float xin[48 * 129];
  __shared__ float rnorm[48];
  __shared__ float cwc[3 * 16 * 64];
  __shared__ float bnr1[256], bnr2[256];
  int tid = threadIdx.x;
  int bb = blockIdx.x >> 4, tcg = blockIdx.x & 15;
  const float* inp = inputs + ((size_t)bb * T_ + (size_t)tcg * 48) * D_;
  for (int idx = tid; idx < 48 * 128; idx += 256) {
    int r = idx >> 7, d = idx & 127;
    xin[r * 129 + d] = inp[idx];
  }
  __syncthreads();
  if (tid < 48) {
    float ss = 0.f;
    for (int d = 0; d < 128; ++d) { float v = xin[tid * 129 + d]; ss += v * v; }
    rnorm[tid] = 1.0f / fmaxf(sqrtf(ss), 1e-12f);
  }
  __syncthreads();
  for (int idx = tid; idx < 48 * 128; idx += 256) {
    int r = idx >> 7, d = idx & 127;
    xin[r * 129 + d] *= rnorm[r];
  }
  int e = tid & 63, tg = tid >> 6;
  float cb = conv_b[e];
  float acc[4];
#pragma unroll
  for (int q = 0; q < 4; ++q) acc[q] = cb;
  for (int ch = 0; ch < 8; ++ch) {
    __syncthreads();
    for (int idx = tid; idx < 3072; idx += 256) {
      int k = idx >> 10; int i2 = idx & 1023; int dd = i2 >> 6; int e2 = i2 & 63;
      cwc[idx] = ws[CWT_OFF + ((size_t)k * D_ + ch * 16 + dd) * E_ + e2];
    }
    __syncthreads();
    for (int dd = 0; dd < 16; ++dd) {
      int dcol = ch * 16 + dd;
#pragma unroll
      for (int k = 0; k < 3; ++k) {
        float w = cwc[(k * 16 + dd) * 64 + e];
#pragma unroll
        for (int q = 0; q < 4; ++q) {
          int tcl = tg * 4 + q;
          acc[q] += w * xin[(3 * tcl + k) * 129 + dcol];
        }
      }
    }
  }
  float ps = 0.f, pss = 0.f;
#pragma unroll
  for (int q = 0; q < 4; ++q) {
    int tcl = tg * 4 + q;
    ws[EMB_OFF + ((size_t)bb * TC_ + tcg * 16 + tcl) * E_ + e] = acc[q];
    ps += acc[q]; pss += acc[q] * acc[q];
  }
  bnr1[tg * 64 + e] = ps;
  bnr2[tg * 64 + e] = pss;
  __syncthreads();
  if (tid < 64) {
    float s1 = bnr1[tid] + bnr1[64 + tid] + bnr1[128 + tid] + bnr1[192 + tid];
    float s2 = bnr2[tid] + bnr2[64 + tid] + bnr2[128 + tid] + bnr2[192 + tid];
    atomicAdd(&ws[SUM_OFF + tid], s1);
    atomicAdd(&ws[SUM_OFF + 64 + tid], s2);
  }
}

// ---------------- BN finalize ----------------
__global__ void bn_finalize_kernel(const float* __restrict__ gamma,
                                   const float* __restrict__ beta,
                                   float* __restrict__ ws) {
  int e = threadIdx.x;
  if (e < 64) {
    const float n = (float)(B_ * TC_);
    float mean = ws[SUM_OFF + e] / n;
    float var = ws[SUM_OFF + 64 + e] / n - mean * mean;
    float sc = gamma[e] * rsqrtf(var + BNEPS);
    ws[SCL_OFF + e] = sc;
    ws[SCL_OFF + 64 + e] = beta[e] - mean * sc;
  }
}

// ---------------- z_x = relu(bn(emb)) @ w_ih^T + b_ih + b_hh ----------------
__global__ __launch_bounds__(256) void zx_kernel(const float* __restrict__ b_ih,
                                                 const float* __restrict__ b_hh,
                                                 float* __restrict__ ws) {
  __shared__ __align__(16) float actT[16 * 64];
  int tid = threadIdx.x;
  int bb = blockIdx.x >> 4, tg2 = blockIdx.x & 15;
  for (int idx = tid; idx < 1024; idx += 256) {
    int tl = idx >> 6, e2 = idx & 63;
    float v = ws[EMB_OFF + ((size_t)bb * TC_ + tg2 * 16 + tl) * E_ + e2];
    actT[idx] = fmaxf(v * ws[SCL_OFF + e2] + ws[SCL_OFF + 64 + e2], 0.f);
  }
  __syncthreads();
  int j0 = tid, j1 = tid + 256;
  float acc0[16], acc1[16];
  float bias0 = b_ih[j0] + b_hh[j0];
  float bias1 = b_ih[j1] + b_hh[j1];
#pragma unroll
  for (int tl = 0; tl < 16; ++tl) { acc0[tl] = bias0; acc1[tl] = bias1; }
  const float* wp = ws + WIH_OFF;
  for (int e4 = 0; e4 < 16; ++e4) {
    float4 w0 = *(const float4*)(wp + ((size_t)e4 * FH_ + j0) * 4);
    float4 w1 = *(const float4*)(wp + ((size_t)e4 * FH_ + j1) * 4);
#pragma unroll
    for (int tl = 0; tl < 16; ++tl) {
      float4 a4 = *(const float4*)(actT + tl * 64 + e4 * 4);
      acc0[tl] += w0.x * a4.x + w0.y * a4.y + w0.z * a4.z + w0.w * a4.w;
      acc1[tl] += w1.x * a4.x + w1.y * a4.y + w1.z * a4.z + w1.w * a4.w;
    }
  }
#pragma unroll
  for (int tl = 0; tl < 16; ++tl) {
    size_t base = ZX_OFF + ((size_t)bb * TC_ + tg2 * 16 + tl) * FH_;
    ws[base + j0] = acc0[tl];
    ws[base + j1] = acc1[tl];
  }
}

// ---------------- Gram tile helper: C tiles via mfma 16x16x32 bf16, split hi/lo ----
template <int NCT>
__device__ inline void gram_do(int rt, int ct0, int lane,
                               const __bf16* GtHi, const __bf16* GtLo,
                               float* M_s, float* y_s) {
  int m = lane & 15, q = lane >> 4;
  floatx4 C[NCT];
#pragma unroll
  for (int ci = 0; ci < NCT; ++ci) C[ci] = (floatx4){0.f, 0.f, 0.f, 0.f};
#pragma unroll
  for (int p = 0; p < 3; ++p) {
    const __bf16* Aa = (p < 2) ? GtHi : GtLo;
    const __bf16* Ba = (p == 1) ? GtLo : GtHi;
    bf16x8 Af[4];
#pragma unroll
    for (int kt = 0; kt < 4; ++kt)
      Af[kt] = *(const bf16x8*)(Aa + (rt * 16 + m) * 136 + kt * 32 + q * 8);
#pragma unroll
    for (int ci = 0; ci < NCT; ++ci) {
#pragma unroll
      for (int kt = 0; kt < 4; ++kt) {
        bf16x8 Bf = *(const bf16x8*)(Ba + ((ct0 + ci) * 16 + m) * 136 + kt * 32 + q * 8);
        C[ci] = __builtin_amdgcn_mfma_f32_16x16x32_bf16(Af[kt], Bf, C[ci], 0, 0, 0);
      }
    }
  }
#pragma unroll
  for (int ci = 0; ci < NCT; ++ci) {
    int ct = ct0 + ci;
#pragma unroll
    for (int reg = 0; reg < 4; ++reg) {
      int grow = rt * 16 + q * 4 + reg;
      if (ct < 4) {
        int gcol = ct * 16 + m;
        M_s[grow * 65 + gcol] = EPSP * C[ci][reg] + ((grow == gcol) ? 1.f : 0.f);
      } else if (m == 0) {
        y_s[grow] = C[ci][reg];   // y = G^T s (unscaled)
      }
    }
  }
}

// consume one float4 of w_hh against 4 broadcast h values
#define FMA4(W, HREG, BOFF)                      \
  acc = fmaf(rl(HREG, (BOFF) + 0), (W).x, acc);  \
  acc = fmaf(rl(HREG, (BOFF) + 1), (W).y, acc);  \
  acc = fmaf(rl(HREG, (BOFF) + 2), (W).z, acc);  \
  acc = fmaf(rl(HREG, (BOFF) + 3), (W).w, acc);

// ---------------- the sequential ProxLSTM scan: 1 block per batch ----------------
// Register budget deliberately <=128/thread: weights are EXPLICITLY streamed from
// L2 with one-chunk-ahead prefetch instead of allocator-spilled "register caches".
__global__ __launch_bounds__(512, 1) void scan_kernel(const float* __restrict__ w_hh,
                                                      const float* __restrict__ lin_w,
                                                      const float* __restrict__ lin_b,
                                                      const float* __restrict__ ws,
                                                      float* __restrict__ out) {
  // bf16 split-precision staging (stride 136/72 keeps b128 bank distribution even)
  __shared__ __align__(16) __bf16 GtHi[80 * 136], GtLo[80 * 136];   // rows 0-63 = G^T[e][h], row 64 = s, 65-79 = 0
  __shared__ __align__(16) __bf16 GntHi[128 * 72], GntLo[128 * 72]; // G[h][e]
  __shared__ __align__(16) __bf16 BxHi[16 * 72], BxLo[16 * 72];     // row 0 = x, rows 1-15 = 0
  __shared__ float M_s[64 * 65];
  __shared__ float Lp_s[16 * 64];
  __shared__ float z_s[512];
  __shared__ float s_s[128], o_s[128], a1_s[128], a2_s[128], a3_s[128];
  __shared__ __align__(16) float c_s[128], h_s[128];
  __shared__ float y_s[64];

  int tid = threadIdx.x;
  int bb = blockIdx.x;
  int lane = tid & 63;
  int wv = tid >> 6;

  int hg = tid >> 5, ep = tid & 31;
  int h0 = hg * 8, e0 = ep * 2;

  const float4* wr = (const float4*)(w_hh + (size_t)tid * H_);
  const float*  wt = ws + WT_OFF;

  // persistent prefetch: first quarter of this thread's w_hh row (32 VGPRs)
  float4 wp[8];
#pragma unroll
  for (int k = 0; k < 8; ++k) wp[k] = wr[k];

  // ---- zero-init LDS constants ----
  for (int i = tid; i < 15 * 136; i += 512) { GtHi[65 * 136 + i] = (__bf16)0.f; GtLo[65 * 136 + i] = (__bf16)0.f; }
  for (int i = tid; i < 15 * 72; i += 512) { BxHi[72 + i] = (__bf16)0.f; BxLo[72 + i] = (__bf16)0.f; }
  if (tid < 128) { c_s[tid] = 0.f; h_s[tid] = 0.f; }

  const float* zxp = ws + ZX_OFF + (size_t)bb * TC_ * FH_;
  float zx0 = 0.f, zx1 = 0.f, zx2 = 0.f, zx3 = 0.f;
  if (tid < 128) {
    zx0 = zxp[tid]; zx1 = zxp[128 + tid]; zx2 = zxp[256 + tid]; zx3 = zxp[384 + tid];
  }
  float dinv = 1.f;   // wave-0: 1/L[lane][lane]
  float4 tv[12];      // streamed G-build weights (48 floats, issued in A, used in stage 2)
  __syncthreads();

  for (int t = 0; t < TC_; ++t) {
    // ---- A: z_s[tid] = w_hh[tid,:] . h  (chunked L2 stream + readlane broadcast) ----
    {
      float hA = h_s[lane];
      float hB = h_s[64 + lane];
      float4 cb1[8], cb2[8];
#pragma unroll
      for (int k = 0; k < 8; ++k) cb1[k] = wr[8 + k];      // issue chunk1
      float acc = 0.f;
#pragma unroll
      for (int k = 0; k < 8; ++k) { FMA4(wp[k], hA, 4 * k) }          // consume persistent
#pragma unroll
      for (int k = 0; k < 8; ++k) cb2[k] = wr[16 + k];     // issue chunk2
#pragma unroll
      for (int k = 0; k < 8; ++k) { FMA4(cb1[k], hA, 32 + 4 * k) }    // consume chunk1
#pragma unroll
      for (int k = 0; k < 8; ++k) cb1[k] = wr[24 + k];     // issue chunk3
#pragma unroll
      for (int k = 0; k < 8; ++k) { FMA4(cb2[k], hB, 4 * k) }         // consume chunk2
#pragma unroll
      for (int k = 0; k < 8; ++k) { FMA4(cb1[k], hB, 32 + 4 * k) }    // consume chunk3
      z_s[tid] = acc;
      // issue G-build weight stream now; consumed in stage 2 (two barriers later)
#pragma unroll
      for (int g = 0; g < 3; ++g)
#pragma unroll
        for (int e = 0; e < 2; ++e)
#pragma unroll
          for (int hf = 0; hf < 2; ++hf)
            tv[g * 4 + e * 2 + hf] =
                *(const float4*)(wt + (size_t)g * 8192 + (size_t)(e0 + e) * 128 + h0 + hf * 4);
    }
    __syncthreads();
    // ---- stage 1 (tid<128): gates, s-row bf16, zx prefetch ----
    if (tid < 128) {
      int h = tid;
      float zi = z_s[h] + zx0, zf = z_s[128 + h] + zx1, zg = z_s[256 + h] + zx2, zo = z_s[384 + h] + zx3;
      float c = c_s[h];
      float ig = fsigmoid(zi);
      float fg = fsigmoid(zf);
      float gg = ftanh(zg);
      float s = fg * c + ig * gg;
      s_s[h] = s;
      o_s[h] = fsigmoid(zo);
      a1_s[h] = ig * (1.f - ig) * gg;
      a2_s[h] = fg * (1.f - fg) * c;
      a3_s[h] = ig * (1.f - gg * gg);
      __bf16 sh = (__bf16)s;
      GtHi[64 * 136 + h] = sh;
      GtLo[64 * 136 + h] = (__bf16)(s - (float)sh);
      if (t + 1 < TC_) {
        const float* zn = zxp + (size_t)(t + 1) * FH_;
        zx0 = zn[h]; zx1 = zn[128 + h]; zx2 = zn[256 + h]; zx3 = zn[384 + h];
      }
    }
    __syncthreads();
    // ---- stage 2 (all): G build from streamed tv -> bf16 split, both layouts ----
    {
      const float* tvf = (const float*)tv;   // tvf[g*16 + e*8 + jj]
      float A1[8], A2[8], A3[8];
      {
        float4 v0 = *(const float4*)(a1_s + h0); float4 v1 = *(const float4*)(a1_s + h0 + 4);
        A1[0] = v0.x; A1[1] = v0.y; A1[2] = v0.z; A1[3] = v0.w;
        A1[4] = v1.x; A1[5] = v1.y; A1[6] = v1.z; A1[7] = v1.w;
        float4 v2 = *(const float4*)(a2_s + h0); float4 v3 = *(const float4*)(a2_s + h0 + 4);
        A2[0] = v2.x; A2[1] = v2.y; A2[2] = v2.z; A2[3] = v2.w;
        A2[4] = v3.x; A2[5] = v3.y; A2[6] = v3.z; A2[7] = v3.w;
        float4 v4 = *(const float4*)(a3_s + h0); float4 v5 = *(const float4*)(a3_s + h0 + 4);
        A3[0] = v4.x; A3[1] = v4.y; A3[2] = v4.z; A3[3] = v4.w;
        A3[4] = v5.x; A3[5] = v5.y; A3[6] = v5.z; A3[7] = v5.w;
      }
      __bf16 ghi[2][8], glo[2][8];
#pragma unroll
      for (int e = 0; e < 2; ++e) {
#pragma unroll
        for (int jj = 0; jj < 8; ++jj) {
          float gv = A1[jj] * tvf[e * 8 + jj] + A2[jj] * tvf[16 + e * 8 + jj] + A3[jj] * tvf[32 + e * 8 + jj];
          __bf16 hi = (__bf16)gv;
          ghi[e][jj] = hi;
          glo[e][jj] = (__bf16)(gv - (float)hi);
        }
      }
#pragma unroll
      for (int jj = 0; jj < 8; ++jj) {
        bf16x2 vh; vh[0] = ghi[0][jj]; vh[1] = ghi[1][jj];
        *(bf16x2*)(&GntHi[(h0 + jj) * 72 + e0]) = vh;
        bf16x2 vl; vl[0] = glo[0][jj]; vl[1] = glo[1][jj];
        *(bf16x2*)(&GntLo[(h0 + jj) * 72 + e0]) = vl;
      }
#pragma unroll
      for (int e = 0; e < 2; ++e) {
        bf16x8 vh, vl;
#pragma unroll
        for (int jj = 0; jj < 8; ++jj) { vh[jj] = ghi[e][jj]; vl[jj] = glo[e][jj]; }
        *(bf16x8*)(&GtHi[(e0 + e) * 136 + h0]) = vh;
        *(bf16x8*)(&GtLo[(e0 + e) * 136 + h0]) = vl;
      }
      // re-issue persistent w_hh chunk for next step; completes during Gram/Cholesky
#pragma unroll
      for (int k = 0; k < 8; ++k) wp[k] = wr[k];
    }
    __syncthreads();
    // ---- Gram via MFMA: M = I + eps*G^T G ; y = G^T s (col 64) ----
    if (wv < 4) gram_do<3>(wv, 0, lane, GtHi, GtLo, M_s, y_s);
    else        gram_do<2>(wv - 4, 3, lane, GtHi, GtLo, M_s, y_s);
    __syncthreads();
    // ---- D: Cholesky (wave 0, panel-16, readlane pivots) + trailing (8 waves) + solves ----
#pragma unroll 1
    for (int pan = 0; pan < 4; ++pan) {
      int j0 = pan * 16;
      if (tid < 64) {
        float p[16];
#pragma unroll
        for (int jj = 0; jj < 16; ++jj) p[jj] = M_s[lane * 65 + j0 + jj];
#pragma unroll
        for (int jj = 0; jj < 16; ++jj) {
          float d  = rl(p[jj], j0 + jj);
          float rs = frsq(d);
          p[jj] *= rs;                         // diag lane: d*rs = sqrt(d)
          dinv = (lane == j0 + jj) ? rs : dinv;
#pragma unroll
          for (int kk = jj + 1; kk < 16; ++kk) {
            float l = rl(p[jj], j0 + kk);
            p[kk] -= p[jj] * l;
          }
        }
#pragma unroll
        for (int jj = 0; jj < 16; ++jj) {
          M_s[lane * 65 + j0 + jj] = p[jj];
          Lp_s[jj * 64 + lane] = p[jj];
        }
        if (pan == 3) {
          float r = y_s[lane];
          // forward: L y' = y
#pragma unroll 16
          for (int i = 0; i < 64; ++i) {
            float Lri = M_s[lane * 65 + i];
            float vv  = rl(r, i) * rl(dinv, i);
            float upd = r - Lri * vv;
            r = (lane == i) ? vv : ((lane > i) ? upd : r);
          }
          // backward: L^T x = y'
#pragma unroll 16
          for (int i = 63; i >= 0; --i) {
            float Lil = M_s[i * 65 + lane];
            float vv  = rl(r, i) * rl(dinv, i);
            float upd = r - Lil * vv;
            r = (lane == i) ? vv : ((lane < i) ? upd : r);
          }
          __bf16 xh = (__bf16)r;
          BxHi[lane] = xh;
          BxLo[lane] = (__bf16)(r - (float)xh);
        }
      }
      __syncthreads();
      if (pan < 3) {
        float Lrow[16];
#pragma unroll
        for (int jj = 0; jj < 16; ++jj) Lrow[jj] = Lp_s[jj * 64 + lane];
        for (int k = j0 + 16 + wv; k < 64; k += 8) {
          float acc = M_s[lane * 65 + k];
#pragma unroll
          for (int jj = 0; jj < 16; ++jj) acc -= Lrow[jj] * Lp_s[jj * 64 + k];
          M_s[lane * 65 + k] = acc;
        }
        __syncthreads();
      }
    }
    // ---- E: u = G x via MFMA; c,h update on col-0 lanes ----
    {
      int m = lane & 15, q = lane >> 4;
      floatx4 C = (floatx4){0.f, 0.f, 0.f, 0.f};
#pragma unroll
      for (int p = 0; p < 3; ++p) {
        const __bf16* Aa = (p < 2) ? GntHi : GntLo;
        const __bf16* Ba = (p == 1) ? BxLo : BxHi;
#pragma unroll
        for (int kt = 0; kt < 2; ++kt) {
          bf16x8 Af = *(const bf16x8*)(Aa + (wv * 16 + m) * 72 + kt * 32 + q * 8);
          bf16x8 Bf = *(const bf16x8*)(Ba + m * 72 + kt * 32 + q * 8);
          C = __builtin_amdgcn_mfma_f32_16x16x32_bf16(Af, Bf, C, 0, 0, 0);
        }
      }
      if (m == 0) {
#pragma unroll
        for (int reg = 0; reg < 4; ++reg) {
          int grow = wv * 16 + q * 4 + reg;
          float u  = C[reg];
          float cn = s_s[grow] - EPSP * u;
          float hn = o_s[grow] * ftanh(cn);
          c_s[grow] = cn;
          h_s[grow] = hn;
        }
      }
    }
    __syncthreads();
  }
  // ---- head ----
  if (tid < O_) {
    float acc = lin_b[tid];
    for (int hh2 = 0; hh2 < 128; ++hh2) acc += h_s[hh2] * lin_w[tid * 128 + hh2];
    out[(size_t)bb * O_ + tid] = acc;
  }
}

// ---------------- launch ----------------
extern "C" void kernel_launch(void* const* d_in, const int* in_sizes, int n_in,
                              void* d_out, int out_size, void* d_ws, size_t ws_size,
                              hipStream_t stream) {
  (void)in_sizes; (void)n_in; (void)out_size;
  const float* inputs  = (const float*)d_in[0];
  const float* conv_w  = (const float*)d_in[2];
  const float* conv_b  = (const float*)d_in[3];
  const float* gamma   = (const float*)d_in[4];
  const float* beta    = (const float*)d_in[5];
  const float* w_ih    = (const float*)d_in[6];
  const float* w_hh    = (const float*)d_in[7];
  const float* b_ih    = (const float*)d_in[8];
  const float* b_hh    = (const float*)d_in[9];
  const float* lin_w   = (const float*)d_in[10];
  const float* lin_b   = (const float*)d_in[11];
  float* out = (float*)d_out;
  float* ws  = (float*)d_ws;

  if (ws_size < WS_FLOATS * sizeof(float)) return;

  hipLaunchKernelGGL(prep_kernel, dim3(192), dim3(256), 0, stream, conv_w, w_ih, ws);
  hipLaunchKernelGGL(conv_bn_kernel, dim3(1024), dim3(256), 0, stream, inputs, conv_b, ws);
  hipLaunchKernelGGL(bn_finalize_kernel, dim3(1), dim3(64), 0, stream, gamma, beta, ws);
  hipLaunchKernelGGL(zx_kernel, dim3(1024), dim3(256), 0, stream, b_ih, b_hh, ws);
  hipLaunchKernelGGL(scan_kernel, dim3(64), dim3(512), 0, stream, w_hh, lin_w, lin_b, ws, out);
}